// Round 8
// baseline (971.032 us; speedup 1.0000x reference)
//
#include <hip/hip_runtime.h>
#include <math.h>

#define HD 64
#define NEGS 0.1f
#define CHUNK 2048
#define NPART 8

typedef unsigned short u16;
typedef unsigned int u32;

__device__ __forceinline__ float leaky(float v) { return v > 0.f ? v : NEGS * v; }

// bf16 helpers: storage bf16, compute fp32.
__device__ __forceinline__ u16 f2bf(float f) {
    union { float f; u32 u; } v; v.f = f;
    u32 r = v.u + 0x7FFFu + ((v.u >> 16) & 1u);   // RNE
    return (u16)(r >> 16);
}
__device__ __forceinline__ float bf2f(u16 u) {
    union { u32 i; float f; } v; v.i = ((u32)u) << 16; return v.f;
}
__device__ __forceinline__ float bflo(u32 x) {
    union { u32 i; float f; } v; v.i = x << 16; return v.f;
}
__device__ __forceinline__ float bfhi(u32 x) {
    union { u32 i; float f; } v; v.i = x & 0xFFFF0000u; return v.f;
}
__device__ __forceinline__ u32 pack2(float a, float b) {
    return (u32)f2bf(a) | ((u32)f2bf(b) << 16);
}

__global__ void zero_i32(int* __restrict__ p, int n) {
    int i = blockIdx.x * blockDim.x + threadIdx.x;
    int stride = gridDim.x * blockDim.x;
    for (; i < n; i += stride) p[i] = 0;
}

// One wave per node; lane = output feature. 2-layer MLP encoder. bf16 out.
template <int IN>
__global__ void encode_k(const float* __restrict__ x,
                         const float* __restrict__ W1, const float* __restrict__ b1,
                         const float* __restrict__ W2, const float* __restrict__ b2,
                         u16* __restrict__ out, int n) {
    __shared__ float sW2[HD * HD];
    for (int idx = threadIdx.x; idx < HD * HD; idx += blockDim.x) sW2[idx] = W2[idx];
    __syncthreads();
    int wave = threadIdx.x >> 6, lane = threadIdx.x & 63;
    int i = blockIdx.x * 4 + wave;
    if (i >= n) return;
    float h1 = b1[lane];
#pragma unroll
    for (int d = 0; d < IN; ++d) h1 += x[i * IN + d] * W1[d * HD + lane];
    h1 = leaky(h1);
    float h2 = b2[lane];
#pragma unroll
    for (int k = 0; k < HD; ++k) {
        float hk = __shfl(h1, k);
        h2 += hk * sW2[k * HD + lane];
    }
    out[i * HD + lane] = f2bf(leaky(h2));
}

// bf16 row copy through object_ptv: uint4 = 8 bf16 per thread-chunk.
__global__ void gather_bf(const u16* __restrict__ enc, const int* __restrict__ ptv,
                          u16* __restrict__ out, int n) {
    int idx = blockIdx.x * blockDim.x + threadIdx.x;
    int stride = gridDim.x * blockDim.x;
    int total = n * (HD / 8);
    for (; idx < total; idx += stride) {
        int i = idx >> 3, ch = idx & 7;
        ((uint4*)(out + (size_t)i * HD))[ch] =
            ((const uint4*)(enc + (size_t)ptv[i] * HD))[ch];
    }
}

// XCD-partitioned histogram: block bid&7 == p handles only dst in partition p.
__global__ void __launch_bounds__(256) hist_part(const int* __restrict__ dst,
                                                 int* __restrict__ counts,
                                                 int E_, int part_sz) {
    int part = blockIdx.x & (NPART - 1);
    int slice = blockIdx.x >> 3;
    int nslices = gridDim.x >> 3;
    int lo = part * part_sz, hi = lo + part_sz;
    for (int e = slice * blockDim.x + threadIdx.x; e < E_; e += nslices * blockDim.x) {
        int d = dst[e];
        if (d >= lo && d < hi) atomicAdd(&counts[d], 1);
    }
}

__global__ void scan1(const int* __restrict__ counts, int* __restrict__ bsum, int n) {
    __shared__ int s[256];
    int b = blockIdx.x, t = threadIdx.x;
    int base = b * CHUNK + t * 8;
    int sum = 0;
#pragma unroll
    for (int u = 0; u < 8; ++u) {
        int i = base + u;
        if (i < n) sum += counts[i];
    }
    s[t] = sum;
    __syncthreads();
    for (int off = 128; off > 0; off >>= 1) {
        if (t < off) s[t] += s[t + off];
        __syncthreads();
    }
    if (t == 0) bsum[b] = s[0];
}

__global__ void scan2(int* __restrict__ bsum, int nb, int* __restrict__ row_ptr, int n) {
    if (threadIdx.x == 0 && blockIdx.x == 0) {
        int run = 0;
        for (int b = 0; b < nb; ++b) {
            int v = bsum[b];
            bsum[b] = run;
            run += v;
        }
        row_ptr[n] = run;
    }
}

__global__ void scan3(const int* __restrict__ counts, const int* __restrict__ bsum,
                      int* __restrict__ row_ptr, int* __restrict__ pos, int n) {
    __shared__ int s[256];
    int b = blockIdx.x, t = threadIdx.x;
    int base = b * CHUNK + t * 8;
    int c[8];
    int sum = 0;
#pragma unroll
    for (int u = 0; u < 8; ++u) {
        int i = base + u;
        c[u] = (i < n) ? counts[i] : 0;
        sum += c[u];
    }
    s[t] = sum;
    __syncthreads();
    for (int off = 1; off < 256; off <<= 1) {
        int v = (t >= off) ? s[t - off] : 0;
        __syncthreads();
        s[t] += v;
        __syncthreads();
    }
    int run = bsum[b] + s[t] - sum;  // exclusive prefix for this thread
#pragma unroll
    for (int u = 0; u < 8; ++u) {
        int i = base + u;
        if (i < n) {
            row_ptr[i] = run;
            pos[i] = run;
            run += c[u];
        }
    }
}

// XCD-partitioned scatter: writes to a csr_col region come from one partition.
__global__ void __launch_bounds__(256) scatter_part(const int* __restrict__ src,
                                                    const int* __restrict__ dst,
                                                    int* __restrict__ pos,
                                                    int* __restrict__ col,
                                                    int E_, int part_sz) {
    int part = blockIdx.x & (NPART - 1);
    int slice = blockIdx.x >> 3;
    int nslices = gridDim.x >> 3;
    int lo = part * part_sz, hi = lo + part_sz;
    for (int e = slice * blockDim.x + threadIdx.x; e < E_; e += nslices * blockDim.x) {
        int d = dst[e];
        if (d >= lo && d < hi) {
            int p = atomicAdd(&pos[d], 1);
            col[p] = src[e];
        }
    }
}

// Fused SAGE layer: per 64-node tile, stage h rows (bf16->f32) into Xs[.][64:128],
// wave-per-node neighbor gather (preloaded idx + shfl, 4 groups x 4 streams,
// fp32 accum) into Xs[.][0:64], then LDS-tiled reg-blocked GEMM vs once-staged
// Ws. 512 threads, 66KB LDS -> 2 blocks/CU; blocks overlap gather/GEMM phases.
__global__ void __launch_bounds__(512) sage_fused(const u16* __restrict__ hin,
                                                  u16* __restrict__ hout,
                                                  const int* __restrict__ row_ptr,
                                                  const int* __restrict__ col,
                                                  const float* __restrict__ Wl,
                                                  const float* __restrict__ Wr,
                                                  const float* __restrict__ bias, int n) {
    __shared__ float Ws[128][64];   // rows 0..63 = Wl, 64..127 = Wr
    __shared__ float Xs[64][132];   // cols 0..63 = agg, 64..127 = h (pad 4)
    int tid = threadIdx.x;
    for (int idx = tid; idx < 64 * 64; idx += 512) {
        int k = idx >> 6, j = idx & 63;
        Ws[k][j] = Wl[idx];
        Ws[64 + k][j] = Wr[idx];
    }
    int wid = tid >> 6, lane = tid & 63;
    int g = lane >> 4, s = lane & 15;
    int tcol = tid & 15, trow = tid >> 4;   // trow 0..31
    int j0 = tcol * 4;
    float b0 = bias[j0], b1 = bias[j0 + 1], b2 = bias[j0 + 2], b3 = bias[j0 + 3];
    int ntiles = (n + 63) >> 6;
    for (int t = blockIdx.x; t < ntiles; t += gridDim.x) {
        int base = t << 6;
        __syncthreads();  // prev GEMM reads done; Xs free (iter0: orders Ws too)
        // stage self rows: row = tid>>3 (0..63), ch = tid&7 (8 bf16 each)
        {
            int row = tid >> 3, ch = tid & 7;
            int grow = base + row;
            uint4 q = make_uint4(0u, 0u, 0u, 0u);
            if (grow < n) q = ((const uint4*)(hin + (size_t)grow * HD))[ch];
            float* xp = &Xs[row][64 + ch * 8];
            xp[0] = bflo(q.x); xp[1] = bfhi(q.x);
            xp[2] = bflo(q.y); xp[3] = bfhi(q.y);
            xp[4] = bflo(q.z); xp[5] = bfhi(q.z);
            xp[6] = bflo(q.w); xp[7] = bfhi(q.w);
        }
        // aggregate: wave wid owns rows base + wid*8 .. +7
        for (int it = 0; it < 8; ++it) {
            int r = wid * 8 + it;
            int grow = base + r;
            if (grow >= n) break;
            int beg = row_ptr[grow], end = row_ptr[grow + 1];
            int deg = end - beg;
            float4 a0 = make_float4(0.f, 0.f, 0.f, 0.f);
            float4 a1 = make_float4(0.f, 0.f, 0.f, 0.f);
            float4 a2 = make_float4(0.f, 0.f, 0.f, 0.f);
            float4 a3 = make_float4(0.f, 0.f, 0.f, 0.f);
            for (int bb = 0; bb < deg; bb += 64) {
                int m = deg - bb;
                if (m > 64) m = 64;
                int cidx = (lane < m) ? col[beg + bb + lane] : 0;
                int k = g;
                for (; k + 12 < m; k += 16) {
                    int c0 = __shfl(cidx, k);
                    int c1 = __shfl(cidx, k + 4);
                    int c2 = __shfl(cidx, k + 8);
                    int c3 = __shfl(cidx, k + 12);
                    uint2 v0 = ((const uint2*)(hin + (size_t)c0 * HD))[s];
                    uint2 v1 = ((const uint2*)(hin + (size_t)c1 * HD))[s];
                    uint2 v2 = ((const uint2*)(hin + (size_t)c2 * HD))[s];
                    uint2 v3 = ((const uint2*)(hin + (size_t)c3 * HD))[s];
                    a0.x += bflo(v0.x); a0.y += bfhi(v0.x); a0.z += bflo(v0.y); a0.w += bfhi(v0.y);
                    a1.x += bflo(v1.x); a1.y += bfhi(v1.x); a1.z += bflo(v1.y); a1.w += bfhi(v1.y);
                    a2.x += bflo(v2.x); a2.y += bfhi(v2.x); a2.z += bflo(v2.y); a2.w += bfhi(v2.y);
                    a3.x += bflo(v3.x); a3.y += bfhi(v3.x); a3.z += bflo(v3.y); a3.w += bfhi(v3.y);
                }
                for (; k < m; k += 4) {
                    int c0 = __shfl(cidx, k);
                    uint2 v0 = ((const uint2*)(hin + (size_t)c0 * HD))[s];
                    a0.x += bflo(v0.x); a0.y += bfhi(v0.x); a0.z += bflo(v0.y); a0.w += bfhi(v0.y);
                }
            }
            a0.x += a1.x + a2.x + a3.x;
            a0.y += a1.y + a2.y + a3.y;
            a0.z += a1.z + a2.z + a3.z;
            a0.w += a1.w + a2.w + a3.w;
            a0.x += __shfl_xor(a0.x, 16);
            a0.y += __shfl_xor(a0.y, 16);
            a0.z += __shfl_xor(a0.z, 16);
            a0.w += __shfl_xor(a0.w, 16);
            a0.x += __shfl_xor(a0.x, 32);
            a0.y += __shfl_xor(a0.y, 32);
            a0.z += __shfl_xor(a0.z, 32);
            a0.w += __shfl_xor(a0.w, 32);
            if (g == 0) *(float4*)&Xs[r][s * 4] = a0;
        }
        __syncthreads();
        // GEMM: thread owns rows trow, trow+32, cols j0..j0+3
        float acc[2][4];
#pragma unroll
        for (int r = 0; r < 2; ++r)
#pragma unroll
            for (int c = 0; c < 4; ++c) acc[r][c] = 0.f;
#pragma unroll 4
        for (int k4 = 0; k4 < 32; ++k4) {
            int k = k4 * 4;
            float4 x0 = *(const float4*)&Xs[trow][k];
            float4 x1 = *(const float4*)&Xs[trow + 32][k];
            float4 w0 = *(const float4*)&Ws[k][j0];
            float4 w1 = *(const float4*)&Ws[k + 1][j0];
            float4 w2 = *(const float4*)&Ws[k + 2][j0];
            float4 w3 = *(const float4*)&Ws[k + 3][j0];
            float4 xr[2] = {x0, x1};
#pragma unroll
            for (int r = 0; r < 2; ++r) {
                acc[r][0] += xr[r].x * w0.x + xr[r].y * w1.x + xr[r].z * w2.x + xr[r].w * w3.x;
                acc[r][1] += xr[r].x * w0.y + xr[r].y * w1.y + xr[r].z * w2.y + xr[r].w * w3.y;
                acc[r][2] += xr[r].x * w0.z + xr[r].y * w1.z + xr[r].z * w2.z + xr[r].w * w3.z;
                acc[r][3] += xr[r].x * w0.w + xr[r].y * w1.w + xr[r].z * w2.w + xr[r].w * w3.w;
            }
        }
#pragma unroll
        for (int r = 0; r < 2; ++r) {
            int grow = base + trow + 32 * r;
            if (grow < n) {
                uint2 o;
                o.x = pack2(leaky(acc[r][0] + b0), leaky(acc[r][1] + b1));
                o.y = pack2(leaky(acc[r][2] + b2), leaky(acc[r][3] + b3));
                *(uint2*)(hout + (size_t)grow * HD + j0) = o;
            }
        }
    }
}

// Last layer rank-1: s_i = h_i . Wl, t_i = h_i . Wr; aggregate scalars.
__global__ void __launch_bounds__(256) dot_bf(const u16* __restrict__ h,
                                              const float* __restrict__ Wl,
                                              const float* __restrict__ Wr,
                                              float* __restrict__ sb, float* __restrict__ tb,
                                              int n) {
    int wid = threadIdx.x >> 6, lane = threadIdx.x & 63;
    float wl = Wl[lane], wr = Wr[lane];
    int wpb = blockDim.x >> 6;
    int stride = gridDim.x * wpb;
    for (int i = blockIdx.x * wpb + wid; i < n; i += stride) {
        float hv = bf2f(h[(size_t)i * HD + lane]);
        float a = hv * wl;
        float c = hv * wr;
#pragma unroll
        for (int off = 32; off > 0; off >>= 1) {
            a += __shfl_xor(a, off);
            c += __shfl_xor(c, off);
        }
        if (lane == 0) {
            sb[i] = a;
            tb[i] = c;
        }
    }
}

__global__ void __launch_bounds__(256) last_k(const float* __restrict__ sb,
                                              const float* __restrict__ tb,
                                              const int* __restrict__ row_ptr,
                                              const int* __restrict__ col,
                                              const float* __restrict__ b_last,
                                              float* __restrict__ out, int n) {
    float b0 = b_last[0];
    int stride = gridDim.x * blockDim.x;
    for (int i = blockIdx.x * blockDim.x + threadIdx.x; i < n; i += stride) {
        int beg = row_ptr[i], end = row_ptr[i + 1];
        float acc = 0.f;
        for (int k = beg; k < end; ++k) acc += sb[col[k]];
        out[i] = 1.f / (1.f + expf(-(acc + tb[i] + b0)));
    }
}

extern "C" void kernel_launch(void* const* d_in, const int* in_sizes, int n_in,
                              void* d_out, int out_size, void* d_ws, size_t ws_size,
                              hipStream_t stream) {
    const float* x_gen = (const float*)d_in[0];
    const float* x_load = (const float*)d_in[1];
    const float* x_or = (const float*)d_in[2];
    const float* x_ex = (const float*)d_in[3];
    const int* edge = (const int*)d_in[4];
    const int* ptv = (const int*)d_in[5];
    const float* W_gen1 = (const float*)d_in[6];
    const float* b_gen1 = (const float*)d_in[7];
    const float* W_gen2 = (const float*)d_in[8];
    const float* b_gen2 = (const float*)d_in[9];
    const float* W_load1 = (const float*)d_in[10];
    const float* b_load1 = (const float*)d_in[11];
    const float* W_load2 = (const float*)d_in[12];
    const float* b_load2 = (const float*)d_in[13];
    const float* W_or1 = (const float*)d_in[14];
    const float* b_or1 = (const float*)d_in[15];
    const float* W_or2 = (const float*)d_in[16];
    const float* b_or2 = (const float*)d_in[17];
    const float* W_ex1 = (const float*)d_in[18];
    const float* b_ex1 = (const float*)d_in[19];
    const float* W_ex2 = (const float*)d_in[20];
    const float* b_ex2 = (const float*)d_in[21];
    const float* Wl_h = (const float*)d_in[22];
    const float* Wr_h = (const float*)d_in[23];
    const float* b_h = (const float*)d_in[24];
    const float* Wl_last = (const float*)d_in[25];
    const float* Wr_last = (const float*)d_in[26];
    const float* b_last = (const float*)d_in[27];

    int n_gen = in_sizes[0] / 3;
    int n_load = in_sizes[1] / 3;
    int n_or = in_sizes[2] / 6;
    int n_ex = in_sizes[3] / 6;
    int E_ = in_sizes[4] / 2;
    int N_ = in_sizes[5];
    const int* srcv = edge;        // row 0
    const int* dstv = edge + E_;   // row 1

    char* ws = (char*)d_ws;
    size_t off = 0;
    auto alloc = [&](size_t bytes) -> void* {
        void* p = ws + off;
        off = (off + bytes + 255) & ~(size_t)255;
        return p;
    };
    u16* enc = (u16*)alloc((size_t)N_ * HD * 2);
    u16* hA = (u16*)alloc((size_t)N_ * HD * 2);
    u16* hB = (u16*)alloc((size_t)N_ * HD * 2);
    int* counts = (int*)alloc((size_t)N_ * 4);
    int* row_ptr = (int*)alloc((size_t)(N_ + 1) * 4);
    int* pos = (int*)alloc((size_t)N_ * 4);
    int* bsum = (int*)alloc(256 * 4);
    int* csr_col = (int*)alloc((size_t)E_ * 4);
    float* sbuf = (float*)alloc((size_t)N_ * 4);
    float* tbuf = (float*)alloc((size_t)N_ * 4);
    (void)ws_size;

    int part_sz = (N_ + NPART - 1) / NPART;

    zero_i32<<<256, 256, 0, stream>>>(counts, N_);

    encode_k<3><<<(n_gen + 3) / 4, 256, 0, stream>>>(x_gen, W_gen1, b_gen1, W_gen2, b_gen2,
                                                     enc, n_gen);
    encode_k<3><<<(n_load + 3) / 4, 256, 0, stream>>>(x_load, W_load1, b_load1, W_load2, b_load2,
                                                      enc + (size_t)n_gen * HD, n_load);
    encode_k<6><<<(n_or + 3) / 4, 256, 0, stream>>>(x_or, W_or1, b_or1, W_or2, b_or2,
                                                    enc + (size_t)(n_gen + n_load) * HD, n_or);
    encode_k<6><<<(n_ex + 3) / 4, 256, 0, stream>>>(x_ex, W_ex1, b_ex1, W_ex2, b_ex2,
                                                    enc + (size_t)(n_gen + n_load + n_or) * HD, n_ex);

    gather_bf<<<1024, 256, 0, stream>>>(enc, ptv, hA, N_);

    hist_part<<<2048, 256, 0, stream>>>(dstv, counts, E_, part_sz);
    int nb = (N_ + CHUNK - 1) / CHUNK;
    scan1<<<nb, 256, 0, stream>>>(counts, bsum, N_);
    scan2<<<1, 64, 0, stream>>>(bsum, nb, row_ptr, N_);
    scan3<<<nb, 256, 0, stream>>>(counts, bsum, row_ptr, pos, N_);
    scatter_part<<<2048, 256, 0, stream>>>(srcv, dstv, pos, csr_col, E_, part_sz);

    int ntiles = (N_ + 63) >> 6;
    int fgrid = ntiles < 512 ? ntiles : 512;
    u16* cur = hA;
    u16* nxt = hB;
    for (int l = 0; l < 7; ++l) {
        sage_fused<<<fgrid, 512, 0, stream>>>(cur, nxt, row_ptr, csr_col,
                                              Wl_h + (size_t)l * HD * HD,
                                              Wr_h + (size_t)l * HD * HD,
                                              b_h + (size_t)l * HD, N_);
        u16* t = cur;
        cur = nxt;
        nxt = t;
    }
    dot_bf<<<1024, 256, 0, stream>>>(cur, Wl_last, Wr_last, sbuf, tbuf, N_);
    last_k<<<512, 256, 0, stream>>>(sbuf, tbuf, row_ptr, csr_col, b_last,
                                    (float*)d_out, N_);
}

// Round 9
// 855.339 us; speedup vs baseline: 1.1353x; 1.1353x over previous
//
#include <hip/hip_runtime.h>
#include <math.h>

#define HD 64
#define NEGS 0.1f
#define CHUNK 2048
#define NPART 8

typedef unsigned short u16;
typedef unsigned int u32;

__device__ __forceinline__ float leaky(float v) { return v > 0.f ? v : NEGS * v; }

// bf16 helpers: storage bf16, compute fp32.
__device__ __forceinline__ u16 f2bf(float f) {
    union { float f; u32 u; } v; v.f = f;
    u32 r = v.u + 0x7FFFu + ((v.u >> 16) & 1u);   // RNE
    return (u16)(r >> 16);
}
__device__ __forceinline__ float bf2f(u16 u) {
    union { u32 i; float f; } v; v.i = ((u32)u) << 16; return v.f;
}
__device__ __forceinline__ float bflo(u32 x) {
    union { u32 i; float f; } v; v.i = x << 16; return v.f;
}
__device__ __forceinline__ float bfhi(u32 x) {
    union { u32 i; float f; } v; v.i = x & 0xFFFF0000u; return v.f;
}
__device__ __forceinline__ u32 pack2(float a, float b) {
    return (u32)f2bf(a) | ((u32)f2bf(b) << 16);
}

__global__ void zero_i32(int* __restrict__ p, int n) {
    int i = blockIdx.x * blockDim.x + threadIdx.x;
    int stride = gridDim.x * blockDim.x;
    for (; i < n; i += stride) p[i] = 0;
}

// One wave per node; lane = output feature. 2-layer MLP encoder. bf16 out.
template <int IN>
__global__ void encode_k(const float* __restrict__ x,
                         const float* __restrict__ W1, const float* __restrict__ b1,
                         const float* __restrict__ W2, const float* __restrict__ b2,
                         u16* __restrict__ out, int n) {
    __shared__ float sW2[HD * HD];
    for (int idx = threadIdx.x; idx < HD * HD; idx += blockDim.x) sW2[idx] = W2[idx];
    __syncthreads();
    int wave = threadIdx.x >> 6, lane = threadIdx.x & 63;
    int i = blockIdx.x * 4 + wave;
    if (i >= n) return;
    float h1 = b1[lane];
#pragma unroll
    for (int d = 0; d < IN; ++d) h1 += x[i * IN + d] * W1[d * HD + lane];
    h1 = leaky(h1);
    float h2 = b2[lane];
#pragma unroll
    for (int k = 0; k < HD; ++k) {
        float hk = __shfl(h1, k);
        h2 += hk * sW2[k * HD + lane];
    }
    out[i * HD + lane] = f2bf(leaky(h2));
}

// bf16 row copy through object_ptv: uint4 = 8 bf16 per thread-chunk.
__global__ void gather_bf(const u16* __restrict__ enc, const int* __restrict__ ptv,
                          u16* __restrict__ out, int n) {
    int idx = blockIdx.x * blockDim.x + threadIdx.x;
    int stride = gridDim.x * blockDim.x;
    int total = n * (HD / 8);
    for (; idx < total; idx += stride) {
        int i = idx >> 3, ch = idx & 7;
        ((uint4*)(out + (size_t)i * HD))[ch] =
            ((const uint4*)(enc + (size_t)ptv[i] * HD))[ch];
    }
}

// XCD-partitioned histogram; streamed dst via NT loads (no L2 pollution).
__global__ void __launch_bounds__(256) hist_part(const int* __restrict__ dst,
                                                 int* __restrict__ counts,
                                                 int E_, int part_sz) {
    int part = blockIdx.x & (NPART - 1);
    int slice = blockIdx.x >> 3;
    int nslices = gridDim.x >> 3;
    int lo = part * part_sz, hi = lo + part_sz;
    for (int e = slice * blockDim.x + threadIdx.x; e < E_; e += nslices * blockDim.x) {
        int d = __builtin_nontemporal_load(&dst[e]);
        if (d >= lo && d < hi) atomicAdd(&counts[d], 1);
    }
}

__global__ void scan1(const int* __restrict__ counts, int* __restrict__ bsum, int n) {
    __shared__ int s[256];
    int b = blockIdx.x, t = threadIdx.x;
    int base = b * CHUNK + t * 8;
    int sum = 0;
#pragma unroll
    for (int u = 0; u < 8; ++u) {
        int i = base + u;
        if (i < n) sum += counts[i];
    }
    s[t] = sum;
    __syncthreads();
    for (int off = 128; off > 0; off >>= 1) {
        if (t < off) s[t] += s[t + off];
        __syncthreads();
    }
    if (t == 0) bsum[b] = s[0];
}

__global__ void scan2(int* __restrict__ bsum, int nb, int* __restrict__ row_ptr, int n) {
    if (threadIdx.x == 0 && blockIdx.x == 0) {
        int run = 0;
        for (int b = 0; b < nb; ++b) {
            int v = bsum[b];
            bsum[b] = run;
            run += v;
        }
        row_ptr[n] = run;
    }
}

__global__ void scan3(const int* __restrict__ counts, const int* __restrict__ bsum,
                      int* __restrict__ row_ptr, int* __restrict__ pos, int n) {
    __shared__ int s[256];
    int b = blockIdx.x, t = threadIdx.x;
    int base = b * CHUNK + t * 8;
    int c[8];
    int sum = 0;
#pragma unroll
    for (int u = 0; u < 8; ++u) {
        int i = base + u;
        c[u] = (i < n) ? counts[i] : 0;
        sum += c[u];
    }
    s[t] = sum;
    __syncthreads();
    for (int off = 1; off < 256; off <<= 1) {
        int v = (t >= off) ? s[t - off] : 0;
        __syncthreads();
        s[t] += v;
        __syncthreads();
    }
    int run = bsum[b] + s[t] - sum;  // exclusive prefix for this thread
#pragma unroll
    for (int u = 0; u < 8; ++u) {
        int i = base + u;
        if (i < n) {
            row_ptr[i] = run;
            pos[i] = run;
            run += c[u];
        }
    }
}

// XCD-partitioned scatter; streamed src/dst via NT loads so partially-filled
// col lines are not evicted from L2 before all 16 slots fill.
__global__ void __launch_bounds__(256) scatter_part(const int* __restrict__ src,
                                                    const int* __restrict__ dst,
                                                    int* __restrict__ pos,
                                                    int* __restrict__ col,
                                                    int E_, int part_sz) {
    int part = blockIdx.x & (NPART - 1);
    int slice = blockIdx.x >> 3;
    int nslices = gridDim.x >> 3;
    int lo = part * part_sz, hi = lo + part_sz;
    for (int e = slice * blockDim.x + threadIdx.x; e < E_; e += nslices * blockDim.x) {
        int d = __builtin_nontemporal_load(&dst[e]);
        if (d >= lo && d < hi) {
            int sv = __builtin_nontemporal_load(&src[e]);
            int p = atomicAdd(&pos[d], 1);
            col[p] = sv;
        }
    }
}

// One wave per node, bf16 rows (128B). Indices preloaded coalesced (NT) + shfl.
// 4 groups x 16 lanes x uint2(4 bf16), 4 streams; fp32 accumulate.
__global__ void __launch_bounds__(256) agg_bf(const u16* __restrict__ hin,
                                              u16* __restrict__ agg,
                                              const int* __restrict__ row_ptr,
                                              const int* __restrict__ col, int n) {
    int wid = threadIdx.x >> 6, lane = threadIdx.x & 63;
    int g = lane >> 4, s = lane & 15;
    int wpb = blockDim.x >> 6;
    int stride = gridDim.x * wpb;
    for (int i = blockIdx.x * wpb + wid; i < n; i += stride) {
        int beg = row_ptr[i], end = row_ptr[i + 1];
        int deg = end - beg;
        float4 a0 = make_float4(0.f, 0.f, 0.f, 0.f);
        float4 a1 = make_float4(0.f, 0.f, 0.f, 0.f);
        float4 a2 = make_float4(0.f, 0.f, 0.f, 0.f);
        float4 a3 = make_float4(0.f, 0.f, 0.f, 0.f);
        for (int base = 0; base < deg; base += 64) {
            int m = deg - base;
            if (m > 64) m = 64;
            int cidx = (lane < m) ? __builtin_nontemporal_load(&col[beg + base + lane]) : 0;
            int k = g;
            for (; k + 12 < m; k += 16) {
                int c0 = __shfl(cidx, k);
                int c1 = __shfl(cidx, k + 4);
                int c2 = __shfl(cidx, k + 8);
                int c3 = __shfl(cidx, k + 12);
                uint2 v0 = ((const uint2*)(hin + (size_t)c0 * HD))[s];
                uint2 v1 = ((const uint2*)(hin + (size_t)c1 * HD))[s];
                uint2 v2 = ((const uint2*)(hin + (size_t)c2 * HD))[s];
                uint2 v3 = ((const uint2*)(hin + (size_t)c3 * HD))[s];
                a0.x += bflo(v0.x); a0.y += bfhi(v0.x); a0.z += bflo(v0.y); a0.w += bfhi(v0.y);
                a1.x += bflo(v1.x); a1.y += bfhi(v1.x); a1.z += bflo(v1.y); a1.w += bfhi(v1.y);
                a2.x += bflo(v2.x); a2.y += bfhi(v2.x); a2.z += bflo(v2.y); a2.w += bfhi(v2.y);
                a3.x += bflo(v3.x); a3.y += bfhi(v3.x); a3.z += bflo(v3.y); a3.w += bfhi(v3.y);
            }
            for (; k < m; k += 4) {
                int c0 = __shfl(cidx, k);
                uint2 v0 = ((const uint2*)(hin + (size_t)c0 * HD))[s];
                a0.x += bflo(v0.x); a0.y += bfhi(v0.x); a0.z += bflo(v0.y); a0.w += bfhi(v0.y);
            }
        }
        a0.x += a1.x + a2.x + a3.x;
        a0.y += a1.y + a2.y + a3.y;
        a0.z += a1.z + a2.z + a3.z;
        a0.w += a1.w + a2.w + a3.w;
        a0.x += __shfl_xor(a0.x, 16);
        a0.y += __shfl_xor(a0.y, 16);
        a0.z += __shfl_xor(a0.z, 16);
        a0.w += __shfl_xor(a0.w, 16);
        a0.x += __shfl_xor(a0.x, 32);
        a0.y += __shfl_xor(a0.y, 32);
        a0.z += __shfl_xor(a0.z, 32);
        a0.w += __shfl_xor(a0.w, 32);
        if (g == 0) {
            uint2 w;
            w.x = pack2(a0.x, a0.y);
            w.y = pack2(a0.z, a0.w);
            ((uint2*)(agg + (size_t)i * HD))[s] = w;
        }
    }
}

// hout = leaky([agg|h] @ [[Wl],[Wr]] + b). bf16 inputs converted during LDS
// staging; inner loop pure fp32 FMA. 64-node tile, 4x4 micro-tile. bf16 out.
__global__ void __launch_bounds__(256) sage_gemm_bf(const u16* __restrict__ agg,
                                                    const u16* __restrict__ h,
                                                    u16* __restrict__ hout,
                                                    const float* __restrict__ Wl,
                                                    const float* __restrict__ Wr,
                                                    const float* __restrict__ bias, int n) {
    __shared__ float Ws[128][64];   // rows 0..63 = Wl, 64..127 = Wr
    __shared__ float Xs[64][132];   // cols 0..63 = agg row, 64..127 = h row (pad 4)
    int tid = threadIdx.x;
    for (int idx = tid; idx < 64 * 64; idx += 256) {
        int k = idx >> 6, j = idx & 63;
        Ws[k][j] = Wl[idx];
        Ws[64 + k][j] = Wr[idx];
    }
    int tcol = tid & 15, trow = tid >> 4;
    int j0 = tcol * 4;
    float b0 = bias[j0], b1 = bias[j0 + 1], b2 = bias[j0 + 2], b3 = bias[j0 + 3];
    int ntiles = (n + 63) >> 6;
    for (int t = blockIdx.x; t < ntiles; t += gridDim.x) {
        int base = t << 6;
        __syncthreads();  // Xs safe to overwrite
#pragma unroll
        for (int u = 0; u < 4; ++u) {
            int idx = tid + u * 256;   // row = idx>>4, chunk = idx&15 (8 bf16 each)
            int row = idx >> 4, ch = idx & 15;
            int grow = base + row;
            uint4 q = make_uint4(0u, 0u, 0u, 0u);
            if (grow < n) {
                q = (ch < 8) ? ((const uint4*)(agg + (size_t)grow * HD))[ch]
                             : ((const uint4*)(h + (size_t)grow * HD))[ch - 8];
            }
            float* xp = &Xs[row][ch * 8];
            xp[0] = bflo(q.x); xp[1] = bfhi(q.x);
            xp[2] = bflo(q.y); xp[3] = bfhi(q.y);
            xp[4] = bflo(q.z); xp[5] = bfhi(q.z);
            xp[6] = bflo(q.w); xp[7] = bfhi(q.w);
        }
        __syncthreads();
        float acc[4][4];
#pragma unroll
        for (int r = 0; r < 4; ++r)
#pragma unroll
            for (int c = 0; c < 4; ++c) acc[r][c] = 0.f;
#pragma unroll 4
        for (int k4 = 0; k4 < 32; ++k4) {
            int k = k4 * 4;
            float4 x0 = *(const float4*)&Xs[trow][k];
            float4 x1 = *(const float4*)&Xs[trow + 16][k];
            float4 x2 = *(const float4*)&Xs[trow + 32][k];
            float4 x3 = *(const float4*)&Xs[trow + 48][k];
            float4 w0 = *(const float4*)&Ws[k][j0];
            float4 w1 = *(const float4*)&Ws[k + 1][j0];
            float4 w2 = *(const float4*)&Ws[k + 2][j0];
            float4 w3 = *(const float4*)&Ws[k + 3][j0];
            float4 xr[4] = {x0, x1, x2, x3};
#pragma unroll
            for (int r = 0; r < 4; ++r) {
                acc[r][0] += xr[r].x * w0.x + xr[r].y * w1.x + xr[r].z * w2.x + xr[r].w * w3.x;
                acc[r][1] += xr[r].x * w0.y + xr[r].y * w1.y + xr[r].z * w2.y + xr[r].w * w3.y;
                acc[r][2] += xr[r].x * w0.z + xr[r].y * w1.z + xr[r].z * w2.z + xr[r].w * w3.z;
                acc[r][3] += xr[r].x * w0.w + xr[r].y * w1.w + xr[r].z * w2.w + xr[r].w * w3.w;
            }
        }
#pragma unroll
        for (int r = 0; r < 4; ++r) {
            int grow = base + trow + 16 * r;
            if (grow < n) {
                uint2 o;
                o.x = pack2(leaky(acc[r][0] + b0), leaky(acc[r][1] + b1));
                o.y = pack2(leaky(acc[r][2] + b2), leaky(acc[r][3] + b3));
                *(uint2*)(hout + (size_t)grow * HD + j0) = o;
            }
        }
    }
}

// Last layer rank-1: s_i = h_i . Wl, t_i = h_i . Wr; aggregate scalars.
__global__ void __launch_bounds__(256) dot_bf(const u16* __restrict__ h,
                                              const float* __restrict__ Wl,
                                              const float* __restrict__ Wr,
                                              float* __restrict__ sb, float* __restrict__ tb,
                                              int n) {
    int wid = threadIdx.x >> 6, lane = threadIdx.x & 63;
    float wl = Wl[lane], wr = Wr[lane];
    int wpb = blockDim.x >> 6;
    int stride = gridDim.x * wpb;
    for (int i = blockIdx.x * wpb + wid; i < n; i += stride) {
        float hv = bf2f(h[(size_t)i * HD + lane]);
        float a = hv * wl;
        float c = hv * wr;
#pragma unroll
        for (int off = 32; off > 0; off >>= 1) {
            a += __shfl_xor(a, off);
            c += __shfl_xor(c, off);
        }
        if (lane == 0) {
            sb[i] = a;
            tb[i] = c;
        }
    }
}

__global__ void __launch_bounds__(256) last_k(const float* __restrict__ sb,
                                              const float* __restrict__ tb,
                                              const int* __restrict__ row_ptr,
                                              const int* __restrict__ col,
                                              const float* __restrict__ b_last,
                                              float* __restrict__ out, int n) {
    float b0 = b_last[0];
    int stride = gridDim.x * blockDim.x;
    for (int i = blockIdx.x * blockDim.x + threadIdx.x; i < n; i += stride) {
        int beg = row_ptr[i], end = row_ptr[i + 1];
        float acc = 0.f;
        for (int k = beg; k < end; ++k) acc += sb[col[k]];
        out[i] = 1.f / (1.f + expf(-(acc + tb[i] + b0)));
    }
}

extern "C" void kernel_launch(void* const* d_in, const int* in_sizes, int n_in,
                              void* d_out, int out_size, void* d_ws, size_t ws_size,
                              hipStream_t stream) {
    const float* x_gen = (const float*)d_in[0];
    const float* x_load = (const float*)d_in[1];
    const float* x_or = (const float*)d_in[2];
    const float* x_ex = (const float*)d_in[3];
    const int* edge = (const int*)d_in[4];
    const int* ptv = (const int*)d_in[5];
    const float* W_gen1 = (const float*)d_in[6];
    const float* b_gen1 = (const float*)d_in[7];
    const float* W_gen2 = (const float*)d_in[8];
    const float* b_gen2 = (const float*)d_in[9];
    const float* W_load1 = (const float*)d_in[10];
    const float* b_load1 = (const float*)d_in[11];
    const float* W_load2 = (const float*)d_in[12];
    const float* b_load2 = (const float*)d_in[13];
    const float* W_or1 = (const float*)d_in[14];
    const float* b_or1 = (const float*)d_in[15];
    const float* W_or2 = (const float*)d_in[16];
    const float* b_or2 = (const float*)d_in[17];
    const float* W_ex1 = (const float*)d_in[18];
    const float* b_ex1 = (const float*)d_in[19];
    const float* W_ex2 = (const float*)d_in[20];
    const float* b_ex2 = (const float*)d_in[21];
    const float* Wl_h = (const float*)d_in[22];
    const float* Wr_h = (const float*)d_in[23];
    const float* b_h = (const float*)d_in[24];
    const float* Wl_last = (const float*)d_in[25];
    const float* Wr_last = (const float*)d_in[26];
    const float* b_last = (const float*)d_in[27];

    int n_gen = in_sizes[0] / 3;
    int n_load = in_sizes[1] / 3;
    int n_or = in_sizes[2] / 6;
    int n_ex = in_sizes[3] / 6;
    int E_ = in_sizes[4] / 2;
    int N_ = in_sizes[5];
    const int* srcv = edge;        // row 0
    const int* dstv = edge + E_;   // row 1

    char* ws = (char*)d_ws;
    size_t off = 0;
    auto alloc = [&](size_t bytes) -> void* {
        void* p = ws + off;
        off = (off + bytes + 255) & ~(size_t)255;
        return p;
    };
    u16* enc = (u16*)alloc((size_t)N_ * HD * 2);   // reused as agg after gather
    u16* hA = (u16*)alloc((size_t)N_ * HD * 2);
    u16* hB = (u16*)alloc((size_t)N_ * HD * 2);
    int* counts = (int*)alloc((size_t)N_ * 4);
    int* row_ptr = (int*)alloc((size_t)(N_ + 1) * 4);
    int* pos = (int*)alloc((size_t)N_ * 4);
    int* bsum = (int*)alloc(256 * 4);
    int* csr_col = (int*)alloc((size_t)E_ * 4);
    float* sbuf = (float*)alloc((size_t)N_ * 4);
    float* tbuf = (float*)alloc((size_t)N_ * 4);
    u16* agg = enc;  // alias: enc is dead after gather_bf
    (void)ws_size;

    int part_sz = (N_ + NPART - 1) / NPART;

    zero_i32<<<256, 256, 0, stream>>>(counts, N_);

    encode_k<3><<<(n_gen + 3) / 4, 256, 0, stream>>>(x_gen, W_gen1, b_gen1, W_gen2, b_gen2,
                                                     enc, n_gen);
    encode_k<3><<<(n_load + 3) / 4, 256, 0, stream>>>(x_load, W_load1, b_load1, W_load2, b_load2,
                                                      enc + (size_t)n_gen * HD, n_load);
    encode_k<6><<<(n_or + 3) / 4, 256, 0, stream>>>(x_or, W_or1, b_or1, W_or2, b_or2,
                                                    enc + (size_t)(n_gen + n_load) * HD, n_or);
    encode_k<6><<<(n_ex + 3) / 4, 256, 0, stream>>>(x_ex, W_ex1, b_ex1, W_ex2, b_ex2,
                                                    enc + (size_t)(n_gen + n_load + n_or) * HD, n_ex);

    gather_bf<<<1024, 256, 0, stream>>>(enc, ptv, hA, N_);

    hist_part<<<2048, 256, 0, stream>>>(dstv, counts, E_, part_sz);
    int nb = (N_ + CHUNK - 1) / CHUNK;
    scan1<<<nb, 256, 0, stream>>>(counts, bsum, N_);
    scan2<<<1, 64, 0, stream>>>(bsum, nb, row_ptr, N_);
    scan3<<<nb, 256, 0, stream>>>(counts, bsum, row_ptr, pos, N_);
    scatter_part<<<2048, 256, 0, stream>>>(srcv, dstv, pos, csr_col, E_, part_sz);

    int ntiles = (N_ + 63) >> 6;
    int ggrid = ntiles < 512 ? ntiles : 512;
    u16* cur = hA;
    u16* nxt = hB;
    for (int l = 0; l < 7; ++l) {
        agg_bf<<<4096, 256, 0, stream>>>(cur, agg, row_ptr, csr_col, N_);
        sage_gemm_bf<<<ggrid, 256, 0, stream>>>(agg, cur, nxt,
                                                Wl_h + (size_t)l * HD * HD,
                                                Wr_h + (size_t)l * HD * HD,
                                                b_h + (size_t)l * HD, N_);
        u16* t = cur;
        cur = nxt;
        nxt = t;
    }
    dot_bf<<<1024, 256, 0, stream>>>(cur, Wl_last, Wr_last, sbuf, tbuf, N_);
    last_k<<<512, 256, 0, stream>>>(sbuf, tbuf, row_ptr, csr_col, b_last,
                                    (float*)d_out, N_);
}

// Round 10
// 835.853 us; speedup vs baseline: 1.1617x; 1.0233x over previous
//
#include <hip/hip_runtime.h>
#include <math.h>

#define HD 64
#define NEGS 0.1f
#define CHUNK 2048
#define NPART 8
#define BK_SLACK 4096

typedef unsigned short u16;
typedef unsigned int u32;

__device__ __forceinline__ float leaky(float v) { return v > 0.f ? v : NEGS * v; }

// bf16 helpers: storage bf16, compute fp32.
__device__ __forceinline__ u16 f2bf(float f) {
    union { float f; u32 u; } v; v.f = f;
    u32 r = v.u + 0x7FFFu + ((v.u >> 16) & 1u);   // RNE
    return (u16)(r >> 16);
}
__device__ __forceinline__ float bf2f(u16 u) {
    union { u32 i; float f; } v; v.i = ((u32)u) << 16; return v.f;
}
__device__ __forceinline__ float bflo(u32 x) {
    union { u32 i; float f; } v; v.i = x << 16; return v.f;
}
__device__ __forceinline__ float bfhi(u32 x) {
    union { u32 i; float f; } v; v.i = x & 0xFFFF0000u; return v.f;
}
__device__ __forceinline__ u32 pack2(float a, float b) {
    return (u32)f2bf(a) | ((u32)f2bf(b) << 16);
}

__global__ void zero_i32(int* __restrict__ p, int n) {
    int i = blockIdx.x * blockDim.x + threadIdx.x;
    int stride = gridDim.x * blockDim.x;
    for (; i < n; i += stride) p[i] = 0;
}

// One wave per node; lane = output feature. 2-layer MLP encoder. bf16 out.
template <int IN>
__global__ void encode_k(const float* __restrict__ x,
                         const float* __restrict__ W1, const float* __restrict__ b1,
                         const float* __restrict__ W2, const float* __restrict__ b2,
                         u16* __restrict__ out, int n) {
    __shared__ float sW2[HD * HD];
    for (int idx = threadIdx.x; idx < HD * HD; idx += blockDim.x) sW2[idx] = W2[idx];
    __syncthreads();
    int wave = threadIdx.x >> 6, lane = threadIdx.x & 63;
    int i = blockIdx.x * 4 + wave;
    if (i >= n) return;
    float h1 = b1[lane];
#pragma unroll
    for (int d = 0; d < IN; ++d) h1 += x[i * IN + d] * W1[d * HD + lane];
    h1 = leaky(h1);
    float h2 = b2[lane];
#pragma unroll
    for (int k = 0; k < HD; ++k) {
        float hk = __shfl(h1, k);
        h2 += hk * sW2[k * HD + lane];
    }
    out[i * HD + lane] = f2bf(leaky(h2));
}

// bf16 row copy through object_ptv: uint4 = 8 bf16 per thread-chunk.
__global__ void gather_bf(const u16* __restrict__ enc, const int* __restrict__ ptv,
                          u16* __restrict__ out, int n) {
    int idx = blockIdx.x * blockDim.x + threadIdx.x;
    int stride = gridDim.x * blockDim.x;
    int total = n * (HD / 8);
    for (; idx < total; idx += stride) {
        int i = idx >> 3, ch = idx & 7;
        ((uint4*)(out + (size_t)i * HD))[ch] =
            ((const uint4*)(enc + (size_t)ptv[i] * HD))[ch];
    }
}

// Phase 1: single-read partition bucketing. Block owns a contiguous edge
// slice; LDS-counts its 8 partition sizes, reserves global ranges (1 atomic
// per partition), then copies (src,dst) into the buckets sequentially.
__global__ void __launch_bounds__(256) bucket1(const int* __restrict__ src,
                                               const int* __restrict__ dst,
                                               int* __restrict__ bsrc,
                                               int* __restrict__ bdst,
                                               int* __restrict__ bcur,
                                               int E_, int part_sz, int cap) {
    __shared__ int lcnt[NPART];
    __shared__ int lbase[NPART];
    int tid = threadIdx.x;
    if (tid < NPART) lcnt[tid] = 0;
    __syncthreads();
    int per = (E_ + gridDim.x - 1) / gridDim.x;
    int s0 = blockIdx.x * per;
    int s1 = s0 + per;
    if (s1 > E_) s1 = E_;
    for (int e = s0 + tid; e < s1; e += 256)
        atomicAdd(&lcnt[dst[e] / part_sz], 1);
    __syncthreads();
    if (tid < NPART) {
        lbase[tid] = atomicAdd(&bcur[tid], lcnt[tid]);
        lcnt[tid] = 0;
    }
    __syncthreads();
    for (int e = s0 + tid; e < s1; e += 256) {
        int d = dst[e];
        int p = d / part_sz;
        int off = atomicAdd(&lcnt[p], 1);
        int slot = p * cap + lbase[p] + off;
        bsrc[slot] = src[e];
        bdst[slot] = d;
    }
}

// Histogram from buckets: block bid&7==p reads bucket p sequentially;
// counts atomics are XCD-local.
__global__ void __launch_bounds__(256) hist_bucket(const int* __restrict__ bdst,
                                                   const int* __restrict__ bcur,
                                                   int* __restrict__ counts, int cap) {
    int p = blockIdx.x & (NPART - 1);
    int slice = blockIdx.x >> 3;
    int nsl = gridDim.x >> 3;
    int cnt = bcur[p];
    const int* bp = bdst + (size_t)p * cap;
    for (int e = slice * 256 + threadIdx.x; e < cnt; e += nsl * 256)
        atomicAdd(&counts[bp[e]], 1);
}

__global__ void scan1(const int* __restrict__ counts, int* __restrict__ bsum, int n) {
    __shared__ int s[256];
    int b = blockIdx.x, t = threadIdx.x;
    int base = b * CHUNK + t * 8;
    int sum = 0;
#pragma unroll
    for (int u = 0; u < 8; ++u) {
        int i = base + u;
        if (i < n) sum += counts[i];
    }
    s[t] = sum;
    __syncthreads();
    for (int off = 128; off > 0; off >>= 1) {
        if (t < off) s[t] += s[t + off];
        __syncthreads();
    }
    if (t == 0) bsum[b] = s[0];
}

__global__ void scan2(int* __restrict__ bsum, int nb, int* __restrict__ row_ptr, int n) {
    if (threadIdx.x == 0 && blockIdx.x == 0) {
        int run = 0;
        for (int b = 0; b < nb; ++b) {
            int v = bsum[b];
            bsum[b] = run;
            run += v;
        }
        row_ptr[n] = run;
    }
}

__global__ void scan3(const int* __restrict__ counts, const int* __restrict__ bsum,
                      int* __restrict__ row_ptr, int* __restrict__ pos, int n) {
    __shared__ int s[256];
    int b = blockIdx.x, t = threadIdx.x;
    int base = b * CHUNK + t * 8;
    int c[8];
    int sum = 0;
#pragma unroll
    for (int u = 0; u < 8; ++u) {
        int i = base + u;
        c[u] = (i < n) ? counts[i] : 0;
        sum += c[u];
    }
    s[t] = sum;
    __syncthreads();
    for (int off = 1; off < 256; off <<= 1) {
        int v = (t >= off) ? s[t - off] : 0;
        __syncthreads();
        s[t] += v;
        __syncthreads();
    }
    int run = bsum[b] + s[t] - sum;  // exclusive prefix for this thread
#pragma unroll
    for (int u = 0; u < 8; ++u) {
        int i = base + u;
        if (i < n) {
            row_ptr[i] = run;
            pos[i] = run;
            run += c[u];
        }
    }
}

// Phase 2: scatter from buckets. Sequential bucket reads; pos atomics and
// col writes confined to partition p's ~800KB region -> XCD-local.
__global__ void __launch_bounds__(256) bucket2(const int* __restrict__ bsrc,
                                               const int* __restrict__ bdst,
                                               const int* __restrict__ bcur,
                                               int* __restrict__ pos,
                                               int* __restrict__ col, int cap) {
    int p = blockIdx.x & (NPART - 1);
    int slice = blockIdx.x >> 3;
    int nsl = gridDim.x >> 3;
    int cnt = bcur[p];
    const int* bs = bsrc + (size_t)p * cap;
    const int* bd = bdst + (size_t)p * cap;
    for (int e = slice * 256 + threadIdx.x; e < cnt; e += nsl * 256) {
        int d = bd[e];
        int sl = atomicAdd(&pos[d], 1);
        col[sl] = bs[e];
    }
}

// One wave per node, bf16 rows (128B). Indices preloaded coalesced + shfl.
// 4 groups x 16 lanes x uint2(4 bf16), 4 streams; fp32 accumulate.
__global__ void __launch_bounds__(256) agg_bf(const u16* __restrict__ hin,
                                              u16* __restrict__ agg,
                                              const int* __restrict__ row_ptr,
                                              const int* __restrict__ col, int n) {
    int wid = threadIdx.x >> 6, lane = threadIdx.x & 63;
    int g = lane >> 4, s = lane & 15;
    int wpb = blockDim.x >> 6;
    int stride = gridDim.x * wpb;
    for (int i = blockIdx.x * wpb + wid; i < n; i += stride) {
        int beg = row_ptr[i], end = row_ptr[i + 1];
        int deg = end - beg;
        float4 a0 = make_float4(0.f, 0.f, 0.f, 0.f);
        float4 a1 = make_float4(0.f, 0.f, 0.f, 0.f);
        float4 a2 = make_float4(0.f, 0.f, 0.f, 0.f);
        float4 a3 = make_float4(0.f, 0.f, 0.f, 0.f);
        for (int base = 0; base < deg; base += 64) {
            int m = deg - base;
            if (m > 64) m = 64;
            int cidx = (lane < m) ? col[beg + base + lane] : 0;
            int k = g;
            for (; k + 12 < m; k += 16) {
                int c0 = __shfl(cidx, k);
                int c1 = __shfl(cidx, k + 4);
                int c2 = __shfl(cidx, k + 8);
                int c3 = __shfl(cidx, k + 12);
                uint2 v0 = ((const uint2*)(hin + (size_t)c0 * HD))[s];
                uint2 v1 = ((const uint2*)(hin + (size_t)c1 * HD))[s];
                uint2 v2 = ((const uint2*)(hin + (size_t)c2 * HD))[s];
                uint2 v3 = ((const uint2*)(hin + (size_t)c3 * HD))[s];
                a0.x += bflo(v0.x); a0.y += bfhi(v0.x); a0.z += bflo(v0.y); a0.w += bfhi(v0.y);
                a1.x += bflo(v1.x); a1.y += bfhi(v1.x); a1.z += bflo(v1.y); a1.w += bfhi(v1.y);
                a2.x += bflo(v2.x); a2.y += bfhi(v2.x); a2.z += bflo(v2.y); a2.w += bfhi(v2.y);
                a3.x += bflo(v3.x); a3.y += bfhi(v3.x); a3.z += bflo(v3.y); a3.w += bfhi(v3.y);
            }
            for (; k < m; k += 4) {
                int c0 = __shfl(cidx, k);
                uint2 v0 = ((const uint2*)(hin + (size_t)c0 * HD))[s];
                a0.x += bflo(v0.x); a0.y += bfhi(v0.x); a0.z += bflo(v0.y); a0.w += bfhi(v0.y);
            }
        }
        a0.x += a1.x + a2.x + a3.x;
        a0.y += a1.y + a2.y + a3.y;
        a0.z += a1.z + a2.z + a3.z;
        a0.w += a1.w + a2.w + a3.w;
        a0.x += __shfl_xor(a0.x, 16);
        a0.y += __shfl_xor(a0.y, 16);
        a0.z += __shfl_xor(a0.z, 16);
        a0.w += __shfl_xor(a0.w, 16);
        a0.x += __shfl_xor(a0.x, 32);
        a0.y += __shfl_xor(a0.y, 32);
        a0.z += __shfl_xor(a0.z, 32);
        a0.w += __shfl_xor(a0.w, 32);
        if (g == 0) {
            uint2 w;
            w.x = pack2(a0.x, a0.y);
            w.y = pack2(a0.z, a0.w);
            ((uint2*)(agg + (size_t)i * HD))[s] = w;
        }
    }
}

// hout = leaky([agg|h] @ [[Wl],[Wr]] + b). bf16 inputs converted during LDS
// staging; inner loop pure fp32 FMA. 64-node tile, 4x4 micro-tile. bf16 out.
__global__ void __launch_bounds__(256) sage_gemm_bf(const u16* __restrict__ agg,
                                                    const u16* __restrict__ h,
                                                    u16* __restrict__ hout,
                                                    const float* __restrict__ Wl,
                                                    const float* __restrict__ Wr,
                                                    const float* __restrict__ bias, int n) {
    __shared__ float Ws[128][64];   // rows 0..63 = Wl, 64..127 = Wr
    __shared__ float Xs[64][132];   // cols 0..63 = agg row, 64..127 = h row (pad 4)
    int tid = threadIdx.x;
    for (int idx = tid; idx < 64 * 64; idx += 256) {
        int k = idx >> 6, j = idx & 63;
        Ws[k][j] = Wl[idx];
        Ws[64 + k][j] = Wr[idx];
    }
    int tcol = tid & 15, trow = tid >> 4;
    int j0 = tcol * 4;
    float b0 = bias[j0], b1 = bias[j0 + 1], b2 = bias[j0 + 2], b3 = bias[j0 + 3];
    int ntiles = (n + 63) >> 6;
    for (int t = blockIdx.x; t < ntiles; t += gridDim.x) {
        int base = t << 6;
        __syncthreads();  // Xs safe to overwrite
#pragma unroll
        for (int u = 0; u < 4; ++u) {
            int idx = tid + u * 256;   // row = idx>>4, chunk = idx&15 (8 bf16 each)
            int row = idx >> 4, ch = idx & 15;
            int grow = base + row;
            uint4 q = make_uint4(0u, 0u, 0u, 0u);
            if (grow < n) {
                q = (ch < 8) ? ((const uint4*)(agg + (size_t)grow * HD))[ch]
                             : ((const uint4*)(h + (size_t)grow * HD))[ch - 8];
            }
            float* xp = &Xs[row][ch * 8];
            xp[0] = bflo(q.x); xp[1] = bfhi(q.x);
            xp[2] = bflo(q.y); xp[3] = bfhi(q.y);
            xp[4] = bflo(q.z); xp[5] = bfhi(q.z);
            xp[6] = bflo(q.w); xp[7] = bfhi(q.w);
        }
        __syncthreads();
        float acc[4][4];
#pragma unroll
        for (int r = 0; r < 4; ++r)
#pragma unroll
            for (int c = 0; c < 4; ++c) acc[r][c] = 0.f;
#pragma unroll 4
        for (int k4 = 0; k4 < 32; ++k4) {
            int k = k4 * 4;
            float4 x0 = *(const float4*)&Xs[trow][k];
            float4 x1 = *(const float4*)&Xs[trow + 16][k];
            float4 x2 = *(const float4*)&Xs[trow + 32][k];
            float4 x3 = *(const float4*)&Xs[trow + 48][k];
            float4 w0 = *(const float4*)&Ws[k][j0];
            float4 w1 = *(const float4*)&Ws[k + 1][j0];
            float4 w2 = *(const float4*)&Ws[k + 2][j0];
            float4 w3 = *(const float4*)&Ws[k + 3][j0];
            float4 xr[4] = {x0, x1, x2, x3};
#pragma unroll
            for (int r = 0; r < 4; ++r) {
                acc[r][0] += xr[r].x * w0.x + xr[r].y * w1.x + xr[r].z * w2.x + xr[r].w * w3.x;
                acc[r][1] += xr[r].x * w0.y + xr[r].y * w1.y + xr[r].z * w2.y + xr[r].w * w3.y;
                acc[r][2] += xr[r].x * w0.z + xr[r].y * w1.z + xr[r].z * w2.z + xr[r].w * w3.z;
                acc[r][3] += xr[r].x * w0.w + xr[r].y * w1.w + xr[r].z * w2.w + xr[r].w * w3.w;
            }
        }
#pragma unroll
        for (int r = 0; r < 4; ++r) {
            int grow = base + trow + 16 * r;
            if (grow < n) {
                uint2 o;
                o.x = pack2(leaky(acc[r][0] + b0), leaky(acc[r][1] + b1));
                o.y = pack2(leaky(acc[r][2] + b2), leaky(acc[r][3] + b3));
                *(uint2*)(hout + (size_t)grow * HD + j0) = o;
            }
        }
    }
}

// Last layer rank-1: s_i = h_i . Wl, t_i = h_i . Wr; aggregate scalars.
__global__ void __launch_bounds__(256) dot_bf(const u16* __restrict__ h,
                                              const float* __restrict__ Wl,
                                              const float* __restrict__ Wr,
                                              float* __restrict__ sb, float* __restrict__ tb,
                                              int n) {
    int wid = threadIdx.x >> 6, lane = threadIdx.x & 63;
    float wl = Wl[lane], wr = Wr[lane];
    int wpb = blockDim.x >> 6;
    int stride = gridDim.x * wpb;
    for (int i = blockIdx.x * wpb + wid; i < n; i += stride) {
        float hv = bf2f(h[(size_t)i * HD + lane]);
        float a = hv * wl;
        float c = hv * wr;
#pragma unroll
        for (int off = 32; off > 0; off >>= 1) {
            a += __shfl_xor(a, off);
            c += __shfl_xor(c, off);
        }
        if (lane == 0) {
            sb[i] = a;
            tb[i] = c;
        }
    }
}

__global__ void __launch_bounds__(256) last_k(const float* __restrict__ sb,
                                              const float* __restrict__ tb,
                                              const int* __restrict__ row_ptr,
                                              const int* __restrict__ col,
                                              const float* __restrict__ b_last,
                                              float* __restrict__ out, int n) {
    float b0 = b_last[0];
    int stride = gridDim.x * blockDim.x;
    for (int i = blockIdx.x * blockDim.x + threadIdx.x; i < n; i += stride) {
        int beg = row_ptr[i], end = row_ptr[i + 1];
        float acc = 0.f;
        for (int k = beg; k < end; ++k) acc += sb[col[k]];
        out[i] = 1.f / (1.f + expf(-(acc + tb[i] + b0)));
    }
}

extern "C" void kernel_launch(void* const* d_in, const int* in_sizes, int n_in,
                              void* d_out, int out_size, void* d_ws, size_t ws_size,
                              hipStream_t stream) {
    const float* x_gen = (const float*)d_in[0];
    const float* x_load = (const float*)d_in[1];
    const float* x_or = (const float*)d_in[2];
    const float* x_ex = (const float*)d_in[3];
    const int* edge = (const int*)d_in[4];
    const int* ptv = (const int*)d_in[5];
    const float* W_gen1 = (const float*)d_in[6];
    const float* b_gen1 = (const float*)d_in[7];
    const float* W_gen2 = (const float*)d_in[8];
    const float* b_gen2 = (const float*)d_in[9];
    const float* W_load1 = (const float*)d_in[10];
    const float* b_load1 = (const float*)d_in[11];
    const float* W_load2 = (const float*)d_in[12];
    const float* b_load2 = (const float*)d_in[13];
    const float* W_or1 = (const float*)d_in[14];
    const float* b_or1 = (const float*)d_in[15];
    const float* W_or2 = (const float*)d_in[16];
    const float* b_or2 = (const float*)d_in[17];
    const float* W_ex1 = (const float*)d_in[18];
    const float* b_ex1 = (const float*)d_in[19];
    const float* W_ex2 = (const float*)d_in[20];
    const float* b_ex2 = (const float*)d_in[21];
    const float* Wl_h = (const float*)d_in[22];
    const float* Wr_h = (const float*)d_in[23];
    const float* b_h = (const float*)d_in[24];
    const float* Wl_last = (const float*)d_in[25];
    const float* Wr_last = (const float*)d_in[26];
    const float* b_last = (const float*)d_in[27];

    int n_gen = in_sizes[0] / 3;
    int n_load = in_sizes[1] / 3;
    int n_or = in_sizes[2] / 6;
    int n_ex = in_sizes[3] / 6;
    int E_ = in_sizes[4] / 2;
    int N_ = in_sizes[5];
    const int* srcv = edge;        // row 0
    const int* dstv = edge + E_;   // row 1

    char* ws = (char*)d_ws;
    size_t off = 0;
    auto alloc = [&](size_t bytes) -> void* {
        void* p = ws + off;
        off = (off + bytes + 255) & ~(size_t)255;
        return p;
    };
    u16* enc = (u16*)alloc((size_t)N_ * HD * 2);   // reused as agg after gather
    u16* hA = (u16*)alloc((size_t)N_ * HD * 2);
    u16* hB = (u16*)alloc((size_t)N_ * HD * 2);
    int* counts = (int*)alloc((size_t)N_ * 4);
    int* row_ptr = (int*)alloc((size_t)(N_ + 1) * 4);
    int* pos = (int*)alloc((size_t)N_ * 4);
    int* bsum = (int*)alloc(256 * 4);
    int* csr_col = (int*)alloc((size_t)E_ * 4);
    float* sbuf = (float*)alloc((size_t)N_ * 4);
    float* tbuf = (float*)alloc((size_t)N_ * 4);
    int part_sz = (N_ + NPART - 1) / NPART;
    int cap = E_ / NPART + BK_SLACK;
    int* bsrc = (int*)alloc((size_t)NPART * cap * 4);
    int* bdst = (int*)alloc((size_t)NPART * cap * 4);
    int* bcur = (int*)alloc(NPART * 4);
    u16* agg = enc;  // alias: enc is dead after gather_bf
    (void)ws_size;

    zero_i32<<<256, 256, 0, stream>>>(counts, N_);
    zero_i32<<<1, 64, 0, stream>>>(bcur, NPART);

    encode_k<3><<<(n_gen + 3) / 4, 256, 0, stream>>>(x_gen, W_gen1, b_gen1, W_gen2, b_gen2,
                                                     enc, n_gen);
    encode_k<3><<<(n_load + 3) / 4, 256, 0, stream>>>(x_load, W_load1, b_load1, W_load2, b_load2,
                                                      enc + (size_t)n_gen * HD, n_load);
    encode_k<6><<<(n_or + 3) / 4, 256, 0, stream>>>(x_or, W_or1, b_or1, W_or2, b_or2,
                                                    enc + (size_t)(n_gen + n_load) * HD, n_or);
    encode_k<6><<<(n_ex + 3) / 4, 256, 0, stream>>>(x_ex, W_ex1, b_ex1, W_ex2, b_ex2,
                                                    enc + (size_t)(n_gen + n_load + n_or) * HD, n_ex);

    gather_bf<<<1024, 256, 0, stream>>>(enc, ptv, hA, N_);

    bucket1<<<1024, 256, 0, stream>>>(srcv, dstv, bsrc, bdst, bcur, E_, part_sz, cap);
    hist_bucket<<<2048, 256, 0, stream>>>(bdst, bcur, counts, cap);
    int nb = (N_ + CHUNK - 1) / CHUNK;
    scan1<<<nb, 256, 0, stream>>>(counts, bsum, N_);
    scan2<<<1, 64, 0, stream>>>(bsum, nb, row_ptr, N_);
    scan3<<<nb, 256, 0, stream>>>(counts, bsum, row_ptr, pos, N_);
    bucket2<<<2048, 256, 0, stream>>>(bsrc, bdst, bcur, pos, csr_col, cap);

    int ntiles = (N_ + 63) >> 6;
    int ggrid = ntiles < 512 ? ntiles : 512;
    u16* cur = hA;
    u16* nxt = hB;
    for (int l = 0; l < 7; ++l) {
        agg_bf<<<4096, 256, 0, stream>>>(cur, agg, row_ptr, csr_col, N_);
        sage_gemm_bf<<<ggrid, 256, 0, stream>>>(agg, cur, nxt,
                                                Wl_h + (size_t)l * HD * HD,
                                                Wr_h + (size_t)l * HD * HD,
                                                b_h + (size_t)l * HD, N_);
        u16* t = cur;
        cur = nxt;
        nxt = t;
    }
    dot_bf<<<1024, 256, 0, stream>>>(cur, Wl_last, Wr_last, sbuf, tbuf, N_);
    last_k<<<512, 256, 0, stream>>>(sbuf, tbuf, row_ptr, csr_col, b_last,
                                    (float*)d_out, N_);
}

// Round 12
// 830.248 us; speedup vs baseline: 1.1696x; 1.0068x over previous
//
#include <hip/hip_runtime.h>
#include <math.h>

#define HD 64
#define NEGS 0.1f
#define CHUNK 2048
#define NPART 8
#define QMAX 440.0f
#define QEPS 1e-30f

typedef unsigned int u32;
typedef unsigned char u8;
typedef float f32x2 __attribute__((ext_vector_type(2)));

__device__ __forceinline__ float leaky(float v) { return v > 0.f ? v : NEGS * v; }

// fp8 e4m3 pack: 4 f32 (already scaled into range) -> u32.
__device__ __forceinline__ u32 pk4(float a, float b, float c, float d) {
    u32 r = __builtin_amdgcn_cvt_pk_fp8_f32(a, b, 0, false);
    r = __builtin_amdgcn_cvt_pk_fp8_f32(c, d, r, true);
    return r;
}

__global__ void zero_i32(int* __restrict__ p, int n) {
    int i = blockIdx.x * blockDim.x + threadIdx.x;
    int stride = gridDim.x * blockDim.x;
    for (; i < n; i += stride) p[i] = 0;
}

// One wave per node; lane = output feature. 2-layer MLP encoder.
// Output: per-row-scaled fp8 + fp32 reciprocal scale.
template <int IN>
__global__ void encode_k(const float* __restrict__ x,
                         const float* __restrict__ W1, const float* __restrict__ b1,
                         const float* __restrict__ W2, const float* __restrict__ b2,
                         u8* __restrict__ out, float* __restrict__ outS, int n) {
    __shared__ float sW2[HD * HD];
    for (int idx = threadIdx.x; idx < HD * HD; idx += blockDim.x) sW2[idx] = W2[idx];
    __syncthreads();
    int wave = threadIdx.x >> 6, lane = threadIdx.x & 63;
    int i = blockIdx.x * 4 + wave;
    if (i >= n) return;
    float h1 = b1[lane];
#pragma unroll
    for (int d = 0; d < IN; ++d) h1 += x[i * IN + d] * W1[d * HD + lane];
    h1 = leaky(h1);
    float h2 = b2[lane];
#pragma unroll
    for (int k = 0; k < HD; ++k) {
        float hk = __shfl(h1, k);
        h2 += hk * sW2[k * HD + lane];
    }
    float val = leaky(h2);
    float am = fabsf(val);
#pragma unroll
    for (int off = 32; off > 0; off >>= 1) am = fmaxf(am, __shfl_xor(am, off));
    float qs, recip;
    if (am < QEPS) { qs = 0.f; recip = 0.f; }
    else { qs = QMAX / am; recip = am / QMAX; }
    float sv = val * qs;
    float v1 = __shfl_down(sv, 1);
    float v2 = __shfl_down(sv, 2);
    float v3 = __shfl_down(sv, 3);
    if ((lane & 3) == 0)
        ((u32*)(out + (size_t)i * HD))[lane >> 2] = pk4(sv, v1, v2, v3);
    if (lane == 0) outS[i] = recip;
}

// fp8 row + scale copy through object_ptv.
__global__ void gather_f8(const u8* __restrict__ enc, const float* __restrict__ encS,
                          const int* __restrict__ ptv,
                          u8* __restrict__ out, float* __restrict__ outS, int n) {
    int idx = blockIdx.x * blockDim.x + threadIdx.x;
    int stride = gridDim.x * blockDim.x;
    int total = n * 4;
    for (; idx < total; idx += stride) {
        int i = idx >> 2, ch = idx & 3;
        int p = ptv[i];
        ((uint4*)(out + (size_t)i * HD))[ch] =
            ((const uint4*)(enc + (size_t)p * HD))[ch];
        if (ch == 0) outS[i] = encS[p];
    }
}

// XCD-partitioned histogram: block bid&7 == p handles only dst in partition p.
__global__ void __launch_bounds__(256) hist_part(const int* __restrict__ dst,
                                                 int* __restrict__ counts,
                                                 int E_, int part_sz) {
    int part = blockIdx.x & (NPART - 1);
    int slice = blockIdx.x >> 3;
    int nslices = gridDim.x >> 3;
    int lo = part * part_sz, hi = lo + part_sz;
    for (int e = slice * blockDim.x + threadIdx.x; e < E_; e += nslices * blockDim.x) {
        int d = dst[e];
        if (d >= lo && d < hi) atomicAdd(&counts[d], 1);
    }
}

__global__ void scan1(const int* __restrict__ counts, int* __restrict__ bsum, int n) {
    __shared__ int s[256];
    int b = blockIdx.x, t = threadIdx.x;
    int base = b * CHUNK + t * 8;
    int sum = 0;
#pragma unroll
    for (int u = 0; u < 8; ++u) {
        int i = base + u;
        if (i < n) sum += counts[i];
    }
    s[t] = sum;
    __syncthreads();
    for (int off = 128; off > 0; off >>= 1) {
        if (t < off) s[t] += s[t + off];
        __syncthreads();
    }
    if (t == 0) bsum[b] = s[0];
}

__global__ void scan2(int* __restrict__ bsum, int nb, int* __restrict__ row_ptr, int n) {
    if (threadIdx.x == 0 && blockIdx.x == 0) {
        int run = 0;
        for (int b = 0; b < nb; ++b) {
            int v = bsum[b];
            bsum[b] = run;
            run += v;
        }
        row_ptr[n] = run;
    }
}

__global__ void scan3(const int* __restrict__ counts, const int* __restrict__ bsum,
                      int* __restrict__ row_ptr, int* __restrict__ pos, int n) {
    __shared__ int s[256];
    int b = blockIdx.x, t = threadIdx.x;
    int base = b * CHUNK + t * 8;
    int c[8];
    int sum = 0;
#pragma unroll
    for (int u = 0; u < 8; ++u) {
        int i = base + u;
        c[u] = (i < n) ? counts[i] : 0;
        sum += c[u];
    }
    s[t] = sum;
    __syncthreads();
    for (int off = 1; off < 256; off <<= 1) {
        int v = (t >= off) ? s[t - off] : 0;
        __syncthreads();
        s[t] += v;
        __syncthreads();
    }
    int run = bsum[b] + s[t] - sum;  // exclusive prefix for this thread
#pragma unroll
    for (int u = 0; u < 8; ++u) {
        int i = base + u;
        if (i < n) {
            row_ptr[i] = run;
            pos[i] = run;
            run += c[u];
        }
    }
}

// XCD-partitioned scatter.
__global__ void __launch_bounds__(256) scatter_part(const int* __restrict__ src,
                                                    const int* __restrict__ dst,
                                                    int* __restrict__ pos,
                                                    int* __restrict__ col,
                                                    int E_, int part_sz) {
    int part = blockIdx.x & (NPART - 1);
    int slice = blockIdx.x >> 3;
    int nslices = gridDim.x >> 3;
    int lo = part * part_sz, hi = lo + part_sz;
    for (int e = slice * blockDim.x + threadIdx.x; e < E_; e += nslices * blockDim.x) {
        int d = dst[e];
        if (d >= lo && d < hi) {
            int p = atomicAdd(&pos[d], 1);
            col[p] = src[e];
        }
    }
}

// One wave per node, fp8 rows (64B = ONE cache line) + per-row scale (L2-hit).
// Indices preloaded coalesced + shfl; 4 groups x 16 lanes x u32, 4 streams;
// fp32 accumulate via FMA with dequant scale; per-row-scaled fp8 out.
__global__ void __launch_bounds__(256) agg_f8(const u8* __restrict__ hin,
                                              const float* __restrict__ hs,
                                              u8* __restrict__ agg,
                                              float* __restrict__ aggS,
                                              const int* __restrict__ row_ptr,
                                              const int* __restrict__ col, int n) {
    int wid = threadIdx.x >> 6, lane = threadIdx.x & 63;
    int g = lane >> 4, s = lane & 15;
    int wpb = blockDim.x >> 6;
    int stride = gridDim.x * wpb;
    for (int i = blockIdx.x * wpb + wid; i < n; i += stride) {
        int beg = row_ptr[i], end = row_ptr[i + 1];
        int deg = end - beg;
        float4 a0 = make_float4(0.f, 0.f, 0.f, 0.f);
        float4 a1 = make_float4(0.f, 0.f, 0.f, 0.f);
        float4 a2 = make_float4(0.f, 0.f, 0.f, 0.f);
        float4 a3 = make_float4(0.f, 0.f, 0.f, 0.f);
        for (int base = 0; base < deg; base += 64) {
            int m = deg - base;
            if (m > 64) m = 64;
            int cidx = (lane < m) ? col[beg + base + lane] : 0;
            int k = g;
            for (; k + 12 < m; k += 16) {
                int c0 = __shfl(cidx, k);
                int c1 = __shfl(cidx, k + 4);
                int c2 = __shfl(cidx, k + 8);
                int c3 = __shfl(cidx, k + 12);
                u32 v0 = ((const u32*)(hin + (size_t)c0 * HD))[s];
                u32 v1 = ((const u32*)(hin + (size_t)c1 * HD))[s];
                u32 v2 = ((const u32*)(hin + (size_t)c2 * HD))[s];
                u32 v3 = ((const u32*)(hin + (size_t)c3 * HD))[s];
                float s0 = hs[c0], s1 = hs[c1], s2 = hs[c2], s3 = hs[c3];
                f32x2 p0 = __builtin_amdgcn_cvt_pk_f32_fp8(v0, false);
                f32x2 q0 = __builtin_amdgcn_cvt_pk_f32_fp8(v0, true);
                f32x2 p1 = __builtin_amdgcn_cvt_pk_f32_fp8(v1, false);
                f32x2 q1 = __builtin_amdgcn_cvt_pk_f32_fp8(v1, true);
                f32x2 p2 = __builtin_amdgcn_cvt_pk_f32_fp8(v2, false);
                f32x2 q2 = __builtin_amdgcn_cvt_pk_f32_fp8(v2, true);
                f32x2 p3 = __builtin_amdgcn_cvt_pk_f32_fp8(v3, false);
                f32x2 q3 = __builtin_amdgcn_cvt_pk_f32_fp8(v3, true);
                a0.x = fmaf(p0.x, s0, a0.x); a0.y = fmaf(p0.y, s0, a0.y);
                a0.z = fmaf(q0.x, s0, a0.z); a0.w = fmaf(q0.y, s0, a0.w);
                a1.x = fmaf(p1.x, s1, a1.x); a1.y = fmaf(p1.y, s1, a1.y);
                a1.z = fmaf(q1.x, s1, a1.z); a1.w = fmaf(q1.y, s1, a1.w);
                a2.x = fmaf(p2.x, s2, a2.x); a2.y = fmaf(p2.y, s2, a2.y);
                a2.z = fmaf(q2.x, s2, a2.z); a2.w = fmaf(q2.y, s2, a2.w);
                a3.x = fmaf(p3.x, s3, a3.x); a3.y = fmaf(p3.y, s3, a3.y);
                a3.z = fmaf(q3.x, s3, a3.z); a3.w = fmaf(q3.y, s3, a3.w);
            }
            for (; k < m; k += 4) {
                int c0 = __shfl(cidx, k);
                u32 v0 = ((const u32*)(hin + (size_t)c0 * HD))[s];
                float s0 = hs[c0];
                f32x2 p0 = __builtin_amdgcn_cvt_pk_f32_fp8(v0, false);
                f32x2 q0 = __builtin_amdgcn_cvt_pk_f32_fp8(v0, true);
                a0.x = fmaf(p0.x, s0, a0.x); a0.y = fmaf(p0.y, s0, a0.y);
                a0.z = fmaf(q0.x, s0, a0.z); a0.w = fmaf(q0.y, s0, a0.w);
            }
        }
        a0.x += a1.x + a2.x + a3.x;
        a0.y += a1.y + a2.y + a3.y;
        a0.z += a1.z + a2.z + a3.z;
        a0.w += a1.w + a2.w + a3.w;
        a0.x += __shfl_xor(a0.x, 16);
        a0.y += __shfl_xor(a0.y, 16);
        a0.z += __shfl_xor(a0.z, 16);
        a0.w += __shfl_xor(a0.w, 16);
        a0.x += __shfl_xor(a0.x, 32);
        a0.y += __shfl_xor(a0.y, 32);
        a0.z += __shfl_xor(a0.z, 32);
        a0.w += __shfl_xor(a0.w, 32);
        // per-row scale: max over the 16 s-slots (each lane holds 4 values)
        float am = fmaxf(fmaxf(fabsf(a0.x), fabsf(a0.y)),
                         fmaxf(fabsf(a0.z), fabsf(a0.w)));
        am = fmaxf(am, __shfl_xor(am, 1));
        am = fmaxf(am, __shfl_xor(am, 2));
        am = fmaxf(am, __shfl_xor(am, 4));
        am = fmaxf(am, __shfl_xor(am, 8));
        float qs, recip;
        if (am < QEPS) { qs = 0.f; recip = 0.f; }
        else { qs = QMAX / am; recip = am / QMAX; }
        if (g == 0) {
            ((u32*)(agg + (size_t)i * HD))[s] =
                pk4(a0.x * qs, a0.y * qs, a0.z * qs, a0.w * qs);
            if (s == 0) aggS[i] = recip;
        }
    }
}

// hout = leaky([agg|h] @ [[Wl],[Wr]] + b), all true-scale fp32 in LDS/regs;
// fp8+scale in, fp8+scale out. 64-node tile, 4x4 micro-tile.
__global__ void __launch_bounds__(256) sage_gemm_f8(const u8* __restrict__ agg,
                                                    const float* __restrict__ aggS,
                                                    const u8* __restrict__ h,
                                                    const float* __restrict__ hS,
                                                    u8* __restrict__ hout,
                                                    float* __restrict__ houtS,
                                                    const float* __restrict__ Wl,
                                                    const float* __restrict__ Wr,
                                                    const float* __restrict__ bias, int n) {
    __shared__ float Ws[128][64];   // rows 0..63 = Wl, 64..127 = Wr
    __shared__ float Xs[64][132];   // cols 0..63 = agg row, 64..127 = h row (pad 4)
    int tid = threadIdx.x;
    for (int idx = tid; idx < 64 * 64; idx += 256) {
        int k = idx >> 6, j = idx & 63;
        Ws[k][j] = Wl[idx];
        Ws[64 + k][j] = Wr[idx];
    }
    int tcol = tid & 15, trow = tid >> 4;
    int j0 = tcol * 4;
    float b0 = bias[j0], b1 = bias[j0 + 1], b2 = bias[j0 + 2], b3 = bias[j0 + 3];
    int ntiles = (n + 63) >> 6;
    for (int t = blockIdx.x; t < ntiles; t += gridDim.x) {
        int base = t << 6;
        __syncthreads();  // Xs safe to overwrite
#pragma unroll
        for (int u = 0; u < 4; ++u) {
            int idx = tid + u * 256;   // row = idx>>4, chunk = idx&15 (8 fp8 each)
            int row = idx >> 4, ch = idx & 15;
            int grow = base + row;
            uint2 q = make_uint2(0u, 0u);
            float sc = 0.f;
            if (grow < n) {
                q = (ch < 8) ? ((const uint2*)(agg + (size_t)grow * HD))[ch]
                             : ((const uint2*)(h + (size_t)grow * HD))[ch - 8];
                sc = (ch < 8) ? aggS[grow] : hS[grow];
            }
            f32x2 p0 = __builtin_amdgcn_cvt_pk_f32_fp8(q.x, false);
            f32x2 p1 = __builtin_amdgcn_cvt_pk_f32_fp8(q.x, true);
            f32x2 p2 = __builtin_amdgcn_cvt_pk_f32_fp8(q.y, false);
            f32x2 p3 = __builtin_amdgcn_cvt_pk_f32_fp8(q.y, true);
            float* xp = &Xs[row][ch * 8];
            xp[0] = p0.x * sc; xp[1] = p0.y * sc; xp[2] = p1.x * sc; xp[3] = p1.y * sc;
            xp[4] = p2.x * sc; xp[5] = p2.y * sc; xp[6] = p3.x * sc; xp[7] = p3.y * sc;
        }
        __syncthreads();
        float acc[4][4];
#pragma unroll
        for (int r = 0; r < 4; ++r)
#pragma unroll
            for (int c = 0; c < 4; ++c) acc[r][c] = 0.f;
#pragma unroll 4
        for (int k4 = 0; k4 < 32; ++k4) {
            int k = k4 * 4;
            float4 x0 = *(const float4*)&Xs[trow][k];
            float4 x1 = *(const float4*)&Xs[trow + 16][k];
            float4 x2 = *(const float4*)&Xs[trow + 32][k];
            float4 x3 = *(const float4*)&Xs[trow + 48][k];
            float4 w0 = *(const float4*)&Ws[k][j0];
            float4 w1 = *(const float4*)&Ws[k + 1][j0];
            float4 w2 = *(const float4*)&Ws[k + 2][j0];
            float4 w3 = *(const float4*)&Ws[k + 3][j0];
            float4 xr[4] = {x0, x1, x2, x3};
#pragma unroll
            for (int r = 0; r < 4; ++r) {
                acc[r][0] += xr[r].x * w0.x + xr[r].y * w1.x + xr[r].z * w2.x + xr[r].w * w3.x;
                acc[r][1] += xr[r].x * w0.y + xr[r].y * w1.y + xr[r].z * w2.y + xr[r].w * w3.y;
                acc[r][2] += xr[r].x * w0.z + xr[r].y * w1.z + xr[r].z * w2.z + xr[r].w * w3.z;
                acc[r][3] += xr[r].x * w0.w + xr[r].y * w1.w + xr[r].z * w2.w + xr[r].w * w3.w;
            }
        }
#pragma unroll
        for (int r = 0; r < 4; ++r) {
            int grow = base + trow + 16 * r;
            float o0 = leaky(acc[r][0] + b0);
            float o1 = leaky(acc[r][1] + b1);
            float o2 = leaky(acc[r][2] + b2);
            float o3 = leaky(acc[r][3] + b3);
            float am = fmaxf(fmaxf(fabsf(o0), fabsf(o1)), fmaxf(fabsf(o2), fabsf(o3)));
            am = fmaxf(am, __shfl_xor(am, 1));
            am = fmaxf(am, __shfl_xor(am, 2));
            am = fmaxf(am, __shfl_xor(am, 4));
            am = fmaxf(am, __shfl_xor(am, 8));
            float qs, recip;
            if (am < QEPS) { qs = 0.f; recip = 0.f; }
            else { qs = QMAX / am; recip = am / QMAX; }
            if (grow < n) {
                ((u32*)(hout + (size_t)grow * HD))[tcol] =
                    pk4(o0 * qs, o1 * qs, o2 * qs, o3 * qs);
                if (tcol == 0) houtS[grow] = recip;
            }
        }
    }
}

// Last layer rank-1: s_i = h_i . Wl, t_i = h_i . Wr.
__global__ void __launch_bounds__(256) dot_f8(const u8* __restrict__ h,
                                              const float* __restrict__ hS,
                                              const float* __restrict__ Wl,
                                              const float* __restrict__ Wr,
                                              float* __restrict__ sb, float* __restrict__ tb,
                                              int n) {
    int wid = threadIdx.x >> 6, lane = threadIdx.x & 63;
    float wl = Wl[lane], wr = Wr[lane];
    int wpb = blockDim.x >> 6;
    int stride = gridDim.x * wpb;
    for (int i = blockIdx.x * wpb + wid; i < n; i += stride) {
        u32 v = ((const u32*)(h + (size_t)i * HD))[lane >> 2];
        float sc = hS[i];
        f32x2 lo = __builtin_amdgcn_cvt_pk_f32_fp8(v, false);
        f32x2 hi = __builtin_amdgcn_cvt_pk_f32_fp8(v, true);
        float hv = ((lane & 2) ? ((lane & 1) ? hi.y : hi.x)
                               : ((lane & 1) ? lo.y : lo.x)) * sc;
        float a = hv * wl;
        float c = hv * wr;
#pragma unroll
        for (int off = 32; off > 0; off >>= 1) {
            a += __shfl_xor(a, off);
            c += __shfl_xor(c, off);
        }
        if (lane == 0) {
            sb[i] = a;
            tb[i] = c;
        }
    }
}

__global__ void __launch_bounds__(256) last_k(const float* __restrict__ sb,
                                              const float* __restrict__ tb,
                                              const int* __restrict__ row_ptr,
                                              const int* __restrict__ col,
                                              const float* __restrict__ b_last,
                                              float* __restrict__ out, int n) {
    float b0 = b_last[0];
    int stride = gridDim.x * blockDim.x;
    for (int i = blockIdx.x * blockDim.x + threadIdx.x; i < n; i += stride) {
        int beg = row_ptr[i], end = row_ptr[i + 1];
        float acc = 0.f;
        for (int k = beg; k < end; ++k) acc += sb[col[k]];
        out[i] = 1.f / (1.f + expf(-(acc + tb[i] + b0)));
    }
}

extern "C" void kernel_launch(void* const* d_in, const int* in_sizes, int n_in,
                              void* d_out, int out_size, void* d_ws, size_t ws_size,
                              hipStream_t stream) {
    const float* x_gen = (const float*)d_in[0];
    const float* x_load = (const float*)d_in[1];
    const float* x_or = (const float*)d_in[2];
    const float* x_ex = (const float*)d_in[3];
    const int* edge = (const int*)d_in[4];
    const int* ptv = (const int*)d_in[5];
    const float* W_gen1 = (const float*)d_in[6];
    const float* b_gen1 = (const float*)d_in[7];
    const float* W_gen2 = (const float*)d_in[8];
    const float* b_gen2 = (const float*)d_in[9];
    const float* W_load1 = (const float*)d_in[10];
    const float* b_load1 = (const float*)d_in[11];
    const float* W_load2 = (const float*)d_in[12];
    const float* b_load2 = (const float*)d_in[13];
    const float* W_or1 = (const float*)d_in[14];
    const float* b_or1 = (const float*)d_in[15];
    const float* W_or2 = (const float*)d_in[16];
    const float* b_or2 = (const float*)d_in[17];
    const float* W_ex1 = (const float*)d_in[18];
    const float* b_ex1 = (const float*)d_in[19];
    const float* W_ex2 = (const float*)d_in[20];
    const float* b_ex2 = (const float*)d_in[21];
    const float* Wl_h = (const float*)d_in[22];
    const float* Wr_h = (const float*)d_in[23];
    const float* b_h = (const float*)d_in[24];
    const float* Wl_last = (const float*)d_in[25];
    const float* Wr_last = (const float*)d_in[26];
    const float* b_last = (const float*)d_in[27];

    int n_gen = in_sizes[0] / 3;
    int n_load = in_sizes[1] / 3;
    int n_or = in_sizes[2] / 6;
    int n_ex = in_sizes[3] / 6;
    int E_ = in_sizes[4] / 2;
    int N_ = in_sizes[5];
    const int* srcv = edge;        // row 0
    const int* dstv = edge + E_;   // row 1

    char* ws = (char*)d_ws;
    size_t off = 0;
    auto alloc = [&](size_t bytes) -> void* {
        void* p = ws + off;
        off = (off + bytes + 255) & ~(size_t)255;
        return p;
    };
    u8* enc = (u8*)alloc((size_t)N_ * HD);        // reused as agg after gather
    float* encS = (float*)alloc((size_t)N_ * 4);  // reused as aggS
    u8* hA = (u8*)alloc((size_t)N_ * HD);
    float* sA = (float*)alloc((size_t)N_ * 4);
    u8* hB = (u8*)alloc((size_t)N_ * HD);
    float* sB = (float*)alloc((size_t)N_ * 4);
    int* counts = (int*)alloc((size_t)N_ * 4);
    int* row_ptr = (int*)alloc((size_t)(N_ + 1) * 4);
    int* pos = (int*)alloc((size_t)N_ * 4);
    int* bsum = (int*)alloc(256 * 4);
    int* csr_col = (int*)alloc((size_t)E_ * 4);
    float* sbuf = (float*)alloc((size_t)N_ * 4);
    float* tbuf = (float*)alloc((size_t)N_ * 4);
    u8* agg = enc;
    float* aggS = encS;
    (void)ws_size;

    int part_sz = (N_ + NPART - 1) / NPART;

    zero_i32<<<256, 256, 0, stream>>>(counts, N_);

    encode_k<3><<<(n_gen + 3) / 4, 256, 0, stream>>>(x_gen, W_gen1, b_gen1, W_gen2, b_gen2,
                                                     enc, encS, n_gen);
    encode_k<3><<<(n_load + 3) / 4, 256, 0, stream>>>(x_load, W_load1, b_load1, W_load2, b_load2,
                                                      enc + (size_t)n_gen * HD, encS + n_gen, n_load);
    encode_k<6><<<(n_or + 3) / 4, 256, 0, stream>>>(x_or, W_or1, b_or1, W_or2, b_or2,
                                                    enc + (size_t)(n_gen + n_load) * HD,
                                                    encS + n_gen + n_load, n_or);
    encode_k<6><<<(n_ex + 3) / 4, 256, 0, stream>>>(x_ex, W_ex1, b_ex1, W_ex2, b_ex2,
                                                    enc + (size_t)(n_gen + n_load + n_or) * HD,
                                                    encS + n_gen + n_load + n_or, n_ex);

    gather_f8<<<512, 256, 0, stream>>>(enc, encS, ptv, hA, sA, N_);

    hist_part<<<2048, 256, 0, stream>>>(dstv, counts, E_, part_sz);
    int nb = (N_ + CHUNK - 1) / CHUNK;
    scan1<<<nb, 256, 0, stream>>>(counts, bsum, N_);
    scan2<<<1, 64, 0, stream>>>(bsum, nb, row_ptr, N_);
    scan3<<<nb, 256, 0, stream>>>(counts, bsum, row_ptr, pos, N_);
    scatter_part<<<2048, 256, 0, stream>>>(srcv, dstv, pos, csr_col, E_, part_sz);

    int ntiles = (N_ + 63) >> 6;
    int ggrid = ntiles < 512 ? ntiles : 512;
    u8* cur = hA;   float* curS = sA;
    u8* nxt = hB;   float* nxtS = sB;
    for (int l = 0; l < 7; ++l) {
        agg_f8<<<4096, 256, 0, stream>>>(cur, curS, agg, aggS, row_ptr, csr_col, N_);
        sage_gemm_f8<<<ggrid, 256, 0, stream>>>(agg, aggS, cur, curS, nxt, nxtS,
                                                Wl_h + (size_t)l * HD * HD,
                                                Wr_h + (size_t)l * HD * HD,
                                                b_h + (size_t)l * HD, N_);
        u8* t = cur; cur = nxt; nxt = t;
        float* ts = curS; curS = nxtS; nxtS = ts;
    }
    dot_f8<<<1024, 256, 0, stream>>>(cur, curS, Wl_last, Wr_last, sbuf, tbuf, N_);
    last_k<<<512, 256, 0, stream>>>(sbuf, tbuf, row_ptr, csr_col, b_last,
                                    (float*)d_out, N_);
}

// Round 13
// 767.034 us; speedup vs baseline: 1.2660x; 1.0824x over previous
//
#include <hip/hip_runtime.h>
#include <math.h>

#define HD 64
#define NEGS 0.1f
#define CHUNK 2048
#define NPART 8
#define QMAX 440.0f
#define QEPS 1e-30f

typedef unsigned int u32;
typedef unsigned char u8;
typedef float f32x2 __attribute__((ext_vector_type(2)));

__device__ __forceinline__ float leaky(float v) { return v > 0.f ? v : NEGS * v; }

// fp8 e4m3 pack: 4 f32 (already scaled into range) -> u32.
__device__ __forceinline__ u32 pk4(float a, float b, float c, float d) {
    u32 r = __builtin_amdgcn_cvt_pk_fp8_f32(a, b, 0, false);
    r = __builtin_amdgcn_cvt_pk_fp8_f32(c, d, r, true);
    return r;
}

__global__ void zero_i32(int* __restrict__ p, int n) {
    int i = blockIdx.x * blockDim.x + threadIdx.x;
    int stride = gridDim.x * blockDim.x;
    for (; i < n; i += stride) p[i] = 0;
}

// One wave per node; lane = output feature. 2-layer MLP encoder.
// Output: per-row-scaled fp8 + fp32 reciprocal scale.
template <int IN>
__global__ void encode_k(const float* __restrict__ x,
                         const float* __restrict__ W1, const float* __restrict__ b1,
                         const float* __restrict__ W2, const float* __restrict__ b2,
                         u8* __restrict__ out, float* __restrict__ outS, int n) {
    __shared__ float sW2[HD * HD];
    for (int idx = threadIdx.x; idx < HD * HD; idx += blockDim.x) sW2[idx] = W2[idx];
    __syncthreads();
    int wave = threadIdx.x >> 6, lane = threadIdx.x & 63;
    int i = blockIdx.x * 4 + wave;
    if (i >= n) return;
    float h1 = b1[lane];
#pragma unroll
    for (int d = 0; d < IN; ++d) h1 += x[i * IN + d] * W1[d * HD + lane];
    h1 = leaky(h1);
    float h2 = b2[lane];
#pragma unroll
    for (int k = 0; k < HD; ++k) {
        float hk = __shfl(h1, k);
        h2 += hk * sW2[k * HD + lane];
    }
    float val = leaky(h2);
    float am = fabsf(val);
#pragma unroll
    for (int off = 32; off > 0; off >>= 1) am = fmaxf(am, __shfl_xor(am, off));
    float qs, recip;
    if (am < QEPS) { qs = 0.f; recip = 0.f; }
    else { qs = QMAX / am; recip = am / QMAX; }
    float sv = val * qs;
    float v1 = __shfl_down(sv, 1);
    float v2 = __shfl_down(sv, 2);
    float v3 = __shfl_down(sv, 3);
    if ((lane & 3) == 0)
        ((u32*)(out + (size_t)i * HD))[lane >> 2] = pk4(sv, v1, v2, v3);
    if (lane == 0) outS[i] = recip;
}

// fp8 row + scale copy through object_ptv.
__global__ void gather_f8(const u8* __restrict__ enc, const float* __restrict__ encS,
                          const int* __restrict__ ptv,
                          u8* __restrict__ out, float* __restrict__ outS, int n) {
    int idx = blockIdx.x * blockDim.x + threadIdx.x;
    int stride = gridDim.x * blockDim.x;
    int total = n * 4;
    for (; idx < total; idx += stride) {
        int i = idx >> 2, ch = idx & 3;
        int p = ptv[i];
        ((uint4*)(out + (size_t)i * HD))[ch] =
            ((const uint4*)(enc + (size_t)p * HD))[ch];
        if (ch == 0) outS[i] = encS[p];
    }
}

// XCD-partitioned histogram: block bid&7 == p handles only dst in partition p.
__global__ void __launch_bounds__(256) hist_part(const int* __restrict__ dst,
                                                 int* __restrict__ counts,
                                                 int E_, int part_sz) {
    int part = blockIdx.x & (NPART - 1);
    int slice = blockIdx.x >> 3;
    int nslices = gridDim.x >> 3;
    int lo = part * part_sz, hi = lo + part_sz;
    for (int e = slice * blockDim.x + threadIdx.x; e < E_; e += nslices * blockDim.x) {
        int d = dst[e];
        if (d >= lo && d < hi) atomicAdd(&counts[d], 1);
    }
}

__global__ void scan1(const int* __restrict__ counts, int* __restrict__ bsum, int n) {
    __shared__ int s[256];
    int b = blockIdx.x, t = threadIdx.x;
    int base = b * CHUNK + t * 8;
    int sum = 0;
#pragma unroll
    for (int u = 0; u < 8; ++u) {
        int i = base + u;
        if (i < n) sum += counts[i];
    }
    s[t] = sum;
    __syncthreads();
    for (int off = 128; off > 0; off >>= 1) {
        if (t < off) s[t] += s[t + off];
        __syncthreads();
    }
    if (t == 0) bsum[b] = s[0];
}

__global__ void scan2(int* __restrict__ bsum, int nb, int* __restrict__ row_ptr, int n) {
    if (threadIdx.x == 0 && blockIdx.x == 0) {
        int run = 0;
        for (int b = 0; b < nb; ++b) {
            int v = bsum[b];
            bsum[b] = run;
            run += v;
        }
        row_ptr[n] = run;
    }
}

__global__ void scan3(const int* __restrict__ counts, const int* __restrict__ bsum,
                      int* __restrict__ row_ptr, int* __restrict__ pos, int n) {
    __shared__ int s[256];
    int b = blockIdx.x, t = threadIdx.x;
    int base = b * CHUNK + t * 8;
    int c[8];
    int sum = 0;
#pragma unroll
    for (int u = 0; u < 8; ++u) {
        int i = base + u;
        c[u] = (i < n) ? counts[i] : 0;
        sum += c[u];
    }
    s[t] = sum;
    __syncthreads();
    for (int off = 1; off < 256; off <<= 1) {
        int v = (t >= off) ? s[t - off] : 0;
        __syncthreads();
        s[t] += v;
        __syncthreads();
    }
    int run = bsum[b] + s[t] - sum;  // exclusive prefix for this thread
#pragma unroll
    for (int u = 0; u < 8; ++u) {
        int i = base + u;
        if (i < n) {
            row_ptr[i] = run;
            pos[i] = run;
            run += c[u];
        }
    }
}

// XCD-partitioned scatter.
__global__ void __launch_bounds__(256) scatter_part(const int* __restrict__ src,
                                                    const int* __restrict__ dst,
                                                    int* __restrict__ pos,
                                                    int* __restrict__ col,
                                                    int E_, int part_sz) {
    int part = blockIdx.x & (NPART - 1);
    int slice = blockIdx.x >> 3;
    int nslices = gridDim.x >> 3;
    int lo = part * part_sz, hi = lo + part_sz;
    for (int e = slice * blockDim.x + threadIdx.x; e < E_; e += nslices * blockDim.x) {
        int d = dst[e];
        if (d >= lo && d < hi) {
            int p = atomicAdd(&pos[d], 1);
            col[p] = src[e];
        }
    }
}

// ONE 16-LANE GROUP PER NODE (4 nodes/wave concurrently). fp8 row = exactly
// 16 lanes x u32, so each lane owns features 4s..4s+3 -> NO cross-group
// reduce, no per-node wave-wide serialization. 4 accumulation streams/lane;
// one VMEM instr still serves 4 (independent) row gathers across the wave.
__global__ void __launch_bounds__(256) agg_f8(const u8* __restrict__ hin,
                                              const float* __restrict__ hs,
                                              u8* __restrict__ agg,
                                              float* __restrict__ aggS,
                                              const int* __restrict__ row_ptr,
                                              const int* __restrict__ col, int n) {
    int tid = threadIdx.x;
    int g = (tid >> 4) & 3;          // group within wave
    int s = tid & 15;                // lane within group
    int gid = (blockIdx.x * blockDim.x + tid) >> 4;   // global group id
    int ngroups = (gridDim.x * blockDim.x) >> 4;
    int gbase = g << 4;              // first lane of this group (within wave)
    for (int i = gid; i < n; i += ngroups) {
        int beg = row_ptr[i], end = row_ptr[i + 1];
        int deg = end - beg;
        float4 a0 = make_float4(0.f, 0.f, 0.f, 0.f);
        float4 a1 = make_float4(0.f, 0.f, 0.f, 0.f);
        float4 a2 = make_float4(0.f, 0.f, 0.f, 0.f);
        float4 a3 = make_float4(0.f, 0.f, 0.f, 0.f);
        for (int base = 0; base < deg; base += 16) {
            int m = deg - base;
            if (m > 16) m = 16;
            int cidx = (s < m) ? col[beg + base + s] : 0;
            int k = 0;
            for (; k + 3 < m; k += 4) {
                int r0 = __shfl(cidx, gbase + k);
                int r1 = __shfl(cidx, gbase + k + 1);
                int r2 = __shfl(cidx, gbase + k + 2);
                int r3 = __shfl(cidx, gbase + k + 3);
                u32 v0 = ((const u32*)(hin + (size_t)r0 * HD))[s];
                u32 v1 = ((const u32*)(hin + (size_t)r1 * HD))[s];
                u32 v2 = ((const u32*)(hin + (size_t)r2 * HD))[s];
                u32 v3 = ((const u32*)(hin + (size_t)r3 * HD))[s];
                float s0 = hs[r0], s1 = hs[r1], s2 = hs[r2], s3 = hs[r3];
                f32x2 p0 = __builtin_amdgcn_cvt_pk_f32_fp8(v0, false);
                f32x2 q0 = __builtin_amdgcn_cvt_pk_f32_fp8(v0, true);
                f32x2 p1 = __builtin_amdgcn_cvt_pk_f32_fp8(v1, false);
                f32x2 q1 = __builtin_amdgcn_cvt_pk_f32_fp8(v1, true);
                f32x2 p2 = __builtin_amdgcn_cvt_pk_f32_fp8(v2, false);
                f32x2 q2 = __builtin_amdgcn_cvt_pk_f32_fp8(v2, true);
                f32x2 p3 = __builtin_amdgcn_cvt_pk_f32_fp8(v3, false);
                f32x2 q3 = __builtin_amdgcn_cvt_pk_f32_fp8(v3, true);
                a0.x = fmaf(p0.x, s0, a0.x); a0.y = fmaf(p0.y, s0, a0.y);
                a0.z = fmaf(q0.x, s0, a0.z); a0.w = fmaf(q0.y, s0, a0.w);
                a1.x = fmaf(p1.x, s1, a1.x); a1.y = fmaf(p1.y, s1, a1.y);
                a1.z = fmaf(q1.x, s1, a1.z); a1.w = fmaf(q1.y, s1, a1.w);
                a2.x = fmaf(p2.x, s2, a2.x); a2.y = fmaf(p2.y, s2, a2.y);
                a2.z = fmaf(q2.x, s2, a2.z); a2.w = fmaf(q2.y, s2, a2.w);
                a3.x = fmaf(p3.x, s3, a3.x); a3.y = fmaf(p3.y, s3, a3.y);
                a3.z = fmaf(q3.x, s3, a3.z); a3.w = fmaf(q3.y, s3, a3.w);
            }
            for (; k < m; ++k) {
                int r0 = __shfl(cidx, gbase + k);
                u32 v0 = ((const u32*)(hin + (size_t)r0 * HD))[s];
                float s0 = hs[r0];
                f32x2 p0 = __builtin_amdgcn_cvt_pk_f32_fp8(v0, false);
                f32x2 q0 = __builtin_amdgcn_cvt_pk_f32_fp8(v0, true);
                a0.x = fmaf(p0.x, s0, a0.x); a0.y = fmaf(p0.y, s0, a0.y);
                a0.z = fmaf(q0.x, s0, a0.z); a0.w = fmaf(q0.y, s0, a0.w);
            }
        }
        a0.x += a1.x + a2.x + a3.x;
        a0.y += a1.y + a2.y + a3.y;
        a0.z += a1.z + a2.z + a3.z;
        a0.w += a1.w + a2.w + a3.w;
        // per-row amax: reduce across the 16-lane group only
        float am = fmaxf(fmaxf(fabsf(a0.x), fabsf(a0.y)),
                         fmaxf(fabsf(a0.z), fabsf(a0.w)));
        am = fmaxf(am, __shfl_xor(am, 1));
        am = fmaxf(am, __shfl_xor(am, 2));
        am = fmaxf(am, __shfl_xor(am, 4));
        am = fmaxf(am, __shfl_xor(am, 8));
        float qs, recip;
        if (am < QEPS) { qs = 0.f; recip = 0.f; }
        else { qs = QMAX / am; recip = am / QMAX; }
        ((u32*)(agg + (size_t)i * HD))[s] =
            pk4(a0.x * qs, a0.y * qs, a0.z * qs, a0.w * qs);
        if (s == 0) aggS[i] = recip;
    }
}

// hout = leaky([agg|h] @ [[Wl],[Wr]] + b), all true-scale fp32 in LDS/regs;
// fp8+scale in, fp8+scale out. 64-node tile, 4x4 micro-tile.
__global__ void __launch_bounds__(256) sage_gemm_f8(const u8* __restrict__ agg,
                                                    const float* __restrict__ aggS,
                                                    const u8* __restrict__ h,
                                                    const float* __restrict__ hS,
                                                    u8* __restrict__ hout,
                                                    float* __restrict__ houtS,
                                                    const float* __restrict__ Wl,
                                                    const float* __restrict__ Wr,
                                                    const float* __restrict__ bias, int n) {
    __shared__ float Ws[128][64];   // rows 0..63 = Wl, 64..127 = Wr
    __shared__ float Xs[64][132];   // cols 0..63 = agg row, 64..127 = h row (pad 4)
    int tid = threadIdx.x;
    for (int idx = tid; idx < 64 * 64; idx += 256) {
        int k = idx >> 6, j = idx & 63;
        Ws[k][j] = Wl[idx];
        Ws[64 + k][j] = Wr[idx];
    }
    int tcol = tid & 15, trow = tid >> 4;
    int j0 = tcol * 4;
    float b0 = bias[j0], b1 = bias[j0 + 1], b2 = bias[j0 + 2], b3 = bias[j0 + 3];
    int ntiles = (n + 63) >> 6;
    for (int t = blockIdx.x; t < ntiles; t += gridDim.x) {
        int base = t << 6;
        __syncthreads();  // Xs safe to overwrite
#pragma unroll
        for (int u = 0; u < 4; ++u) {
            int idx = tid + u * 256;   // row = idx>>4, chunk = idx&15 (8 fp8 each)
            int row = idx >> 4, ch = idx & 15;
            int grow = base + row;
            uint2 q = make_uint2(0u, 0u);
            float sc = 0.f;
            if (grow < n) {
                q = (ch < 8) ? ((const uint2*)(agg + (size_t)grow * HD))[ch]
                             : ((const uint2*)(h + (size_t)grow * HD))[ch - 8];
                sc = (ch < 8) ? aggS[grow] : hS[grow];
            }
            f32x2 p0 = __builtin_amdgcn_cvt_pk_f32_fp8(q.x, false);
            f32x2 p1 = __builtin_amdgcn_cvt_pk_f32_fp8(q.x, true);
            f32x2 p2 = __builtin_amdgcn_cvt_pk_f32_fp8(q.y, false);
            f32x2 p3 = __builtin_amdgcn_cvt_pk_f32_fp8(q.y, true);
            float* xp = &Xs[row][ch * 8];
            xp[0] = p0.x * sc; xp[1] = p0.y * sc; xp[2] = p1.x * sc; xp[3] = p1.y * sc;
            xp[4] = p2.x * sc; xp[5] = p2.y * sc; xp[6] = p3.x * sc; xp[7] = p3.y * sc;
        }
        __syncthreads();
        float acc[4][4];
#pragma unroll
        for (int r = 0; r < 4; ++r)
#pragma unroll
            for (int c = 0; c < 4; ++c) acc[r][c] = 0.f;
#pragma unroll 4
        for (int k4 = 0; k4 < 32; ++k4) {
            int k = k4 * 4;
            float4 x0 = *(const float4*)&Xs[trow][k];
            float4 x1 = *(const float4*)&Xs[trow + 16][k];
            float4 x2 = *(const float4*)&Xs[trow + 32][k];
            float4 x3 = *(const float4*)&Xs[trow + 48][k];
            float4 w0 = *(const float4*)&Ws[k][j0];
            float4 w1 = *(const float4*)&Ws[k + 1][j0];
            float4 w2 = *(const float4*)&Ws[k + 2][j0];
            float4 w3 = *(const float4*)&Ws[k + 3][j0];
            float4 xr[4] = {x0, x1, x2, x3};
#pragma unroll
            for (int r = 0; r < 4; ++r) {
                acc[r][0] += xr[r].x * w0.x + xr[r].y * w1.x + xr[r].z * w2.x + xr[r].w * w3.x;
                acc[r][1] += xr[r].x * w0.y + xr[r].y * w1.y + xr[r].z * w2.y + xr[r].w * w3.y;
                acc[r][2] += xr[r].x * w0.z + xr[r].y * w1.z + xr[r].z * w2.z + xr[r].w * w3.z;
                acc[r][3] += xr[r].x * w0.w + xr[r].y * w1.w + xr[r].z * w2.w + xr[r].w * w3.w;
            }
        }
#pragma unroll
        for (int r = 0; r < 4; ++r) {
            int grow = base + trow + 16 * r;
            float o0 = leaky(acc[r][0] + b0);
            float o1 = leaky(acc[r][1] + b1);
            float o2 = leaky(acc[r][2] + b2);
            float o3 = leaky(acc[r][3] + b3);
            float am = fmaxf(fmaxf(fabsf(o0), fabsf(o1)), fmaxf(fabsf(o2), fabsf(o3)));
            am = fmaxf(am, __shfl_xor(am, 1));
            am = fmaxf(am, __shfl_xor(am, 2));
            am = fmaxf(am, __shfl_xor(am, 4));
            am = fmaxf(am, __shfl_xor(am, 8));
            float qs, recip;
            if (am < QEPS) { qs = 0.f; recip = 0.f; }
            else { qs = QMAX / am; recip = am / QMAX; }
            if (grow < n) {
                ((u32*)(hout + (size_t)grow * HD))[tcol] =
                    pk4(o0 * qs, o1 * qs, o2 * qs, o3 * qs);
                if (tcol == 0) houtS[grow] = recip;
            }
        }
    }
}

// Last layer rank-1: s_i = h_i . Wl, t_i = h_i . Wr.
__global__ void __launch_bounds__(256) dot_f8(const u8* __restrict__ h,
                                              const float* __restrict__ hS,
                                              const float* __restrict__ Wl,
                                              const float* __restrict__ Wr,
                                              float* __restrict__ sb, float* __restrict__ tb,
                                              int n) {
    int wid = threadIdx.x >> 6, lane = threadIdx.x & 63;
    float wl = Wl[lane], wr = Wr[lane];
    int wpb = blockDim.x >> 6;
    int stride = gridDim.x * wpb;
    for (int i = blockIdx.x * wpb + wid; i < n; i += stride) {
        u32 v = ((const u32*)(h + (size_t)i * HD))[lane >> 2];
        float sc = hS[i];
        f32x2 lo = __builtin_amdgcn_cvt_pk_f32_fp8(v, false);
        f32x2 hi = __builtin_amdgcn_cvt_pk_f32_fp8(v, true);
        float hv = ((lane & 2) ? ((lane & 1) ? hi.y : hi.x)
                               : ((lane & 1) ? lo.y : lo.x)) * sc;
        float a = hv * wl;
        float c = hv * wr;
#pragma unroll
        for (int off = 32; off > 0; off >>= 1) {
            a += __shfl_xor(a, off);
            c += __shfl_xor(c, off);
        }
        if (lane == 0) {
            sb[i] = a;
            tb[i] = c;
        }
    }
}

__global__ void __launch_bounds__(256) last_k(const float* __restrict__ sb,
                                              const float* __restrict__ tb,
                                              const int* __restrict__ row_ptr,
                                              const int* __restrict__ col,
                                              const float* __restrict__ b_last,
                                              float* __restrict__ out, int n) {
    float b0 = b_last[0];
    int stride = gridDim.x * blockDim.x;
    for (int i = blockIdx.x * blockDim.x + threadIdx.x; i < n; i += stride) {
        int beg = row_ptr[i], end = row_ptr[i + 1];
        float acc = 0.f;
        for (int k = beg; k < end; ++k) acc += sb[col[k]];
        out[i] = 1.f / (1.f + expf(-(acc + tb[i] + b0)));
    }
}

extern "C" void kernel_launch(void* const* d_in, const int* in_sizes, int n_in,
                              void* d_out, int out_size, void* d_ws, size_t ws_size,
                              hipStream_t stream) {
    const float* x_gen = (const float*)d_in[0];
    const float* x_load = (const float*)d_in[1];
    const float* x_or = (const float*)d_in[2];
    const float* x_ex = (const float*)d_in[3];
    const int* edge = (const int*)d_in[4];
    const int* ptv = (const int*)d_in[5];
    const float* W_gen1 = (const float*)d_in[6];
    const float* b_gen1 = (const float*)d_in[7];
    const float* W_gen2 = (const float*)d_in[8];
    const float* b_gen2 = (const float*)d_in[9];
    const float* W_load1 = (const float*)d_in[10];
    const float* b_load1 = (const float*)d_in[11];
    const float* W_load2 = (const float*)d_in[12];
    const float* b_load2 = (const float*)d_in[13];
    const float* W_or1 = (const float*)d_in[14];
    const float* b_or1 = (const float*)d_in[15];
    const float* W_or2 = (const float*)d_in[16];
    const float* b_or2 = (const float*)d_in[17];
    const float* W_ex1 = (const float*)d_in[18];
    const float* b_ex1 = (const float*)d_in[19];
    const float* W_ex2 = (const float*)d_in[20];
    const float* b_ex2 = (const float*)d_in[21];
    const float* Wl_h = (const float*)d_in[22];
    const float* Wr_h = (const float*)d_in[23];
    const float* b_h = (const float*)d_in[24];
    const float* Wl_last = (const float*)d_in[25];
    const float* Wr_last = (const float*)d_in[26];
    const float* b_last = (const float*)d_in[27];

    int n_gen = in_sizes[0] / 3;
    int n_load = in_sizes[1] / 3;
    int n_or = in_sizes[2] / 6;
    int n_ex = in_sizes[3] / 6;
    int E_ = in_sizes[4] / 2;
    int N_ = in_sizes[5];
    const int* srcv = edge;        // row 0
    const int* dstv = edge + E_;   // row 1

    char* ws = (char*)d_ws;
    size_t off = 0;
    auto alloc = [&](size_t bytes) -> void* {
        void* p = ws + off;
        off = (off + bytes + 255) & ~(size_t)255;
        return p;
    };
    u8* enc = (u8*)alloc((size_t)N_ * HD);        // reused as agg after gather
    float* encS = (float*)alloc((size_t)N_ * 4);  // reused as aggS
    u8* hA = (u8*)alloc((size_t)N_ * HD);
    float* sA = (float*)alloc((size_t)N_ * 4);
    u8* hB = (u8*)alloc((size_t)N_ * HD);
    float* sB = (float*)alloc((size_t)N_ * 4);
    int* counts = (int*)alloc((size_t)N_ * 4);
    int* row_ptr = (int*)alloc((size_t)(N_ + 1) * 4);
    int* pos = (int*)alloc((size_t)N_ * 4);
    int* bsum = (int*)alloc(256 * 4);
    int* csr_col = (int*)alloc((size_t)E_ * 4);
    float* sbuf = (float*)alloc((size_t)N_ * 4);
    float* tbuf = (float*)alloc((size_t)N_ * 4);
    u8* agg = enc;
    float* aggS = encS;
    (void)ws_size;

    int part_sz = (N_ + NPART - 1) / NPART;

    zero_i32<<<256, 256, 0, stream>>>(counts, N_);

    encode_k<3><<<(n_gen + 3) / 4, 256, 0, stream>>>(x_gen, W_gen1, b_gen1, W_gen2, b_gen2,
                                                     enc, encS, n_gen);
    encode_k<3><<<(n_load + 3) / 4, 256, 0, stream>>>(x_load, W_load1, b_load1, W_load2, b_load2,
                                                      enc + (size_t)n_gen * HD, encS + n_gen, n_load);
    encode_k<6><<<(n_or + 3) / 4, 256, 0, stream>>>(x_or, W_or1, b_or1, W_or2, b_or2,
                                                    enc + (size_t)(n_gen + n_load) * HD,
                                                    encS + n_gen + n_load, n_or);
    encode_k<6><<<(n_ex + 3) / 4, 256, 0, stream>>>(x_ex, W_ex1, b_ex1, W_ex2, b_ex2,
                                                    enc + (size_t)(n_gen + n_load + n_or) * HD,
                                                    encS + n_gen + n_load + n_or, n_ex);

    gather_f8<<<512, 256, 0, stream>>>(enc, encS, ptv, hA, sA, N_);

    hist_part<<<2048, 256, 0, stream>>>(dstv, counts, E_, part_sz);
    int nb = (N_ + CHUNK - 1) / CHUNK;
    scan1<<<nb, 256, 0, stream>>>(counts, bsum, N_);
    scan2<<<1, 64, 0, stream>>>(bsum, nb, row_ptr, N_);
    scan3<<<nb, 256, 0, stream>>>(counts, bsum, row_ptr, pos, N_);
    scatter_part<<<2048, 256, 0, stream>>>(srcv, dstv, pos, csr_col, E_, part_sz);

    int ntiles = (N_ + 63) >> 6;
    int ggrid = ntiles < 512 ? ntiles : 512;
    int agrid = (N_ + 15) / 16;          // one 16-lane group per node
    if (agrid > 6250) agrid = 6250;
    u8* cur = hA;   float* curS = sA;
    u8* nxt = hB;   float* nxtS = sB;
    for (int l = 0; l < 7; ++l) {
        agg_f8<<<agrid, 256, 0, stream>>>(cur, curS, agg, aggS, row_ptr, csr_col, N_);
        sage_gemm_f8<<<ggrid, 256, 0, stream>>>(agg, aggS, cur, curS, nxt, nxtS,
                                                Wl_h + (size_t)l * HD * HD,
                                                Wr_h + (size_t)l * HD * HD,
                                                b_h + (size_t)l * HD, N_);
        u8* t = cur; cur = nxt; nxt = t;
        float* ts = curS; curS = nxtS; nxtS = ts;
    }
    dot_f8<<<1024, 256, 0, stream>>>(cur, curS, Wl_last, Wr_last, sbuf, tbuf, N_);
    last_k<<<512, 256, 0, stream>>>(sbuf, tbuf, row_ptr, csr_col, b_last,
                                    (float*)d_out, N_);
}